// Round 6
// baseline (909.254 us; speedup 1.0000x reference)
//
#include <hip/hip_runtime.h>
#include <cstdint>

constexpr int kDM = 2048;   // d_model
constexpr int kNH = 16;     // heads
constexpr int kDH = 128;    // head dim
constexpr int kS  = 2048;   // seq
constexpr int kM  = 4096;   // B*S rows

typedef __bf16 bf16x8 __attribute__((ext_vector_type(8)));
typedef float  f32x4  __attribute__((ext_vector_type(4)));

__device__ __forceinline__ unsigned short f2bf(float f) {
    union { float f; unsigned u; } v; v.f = f;
    unsigned u = v.u;
    u += 0x7fffu + ((u >> 16) & 1u);   // RNE
    return (unsigned short)(u >> 16);
}
__device__ __forceinline__ float bf2f(unsigned short b) {
    union { unsigned u; float f; } v; v.u = ((unsigned)b) << 16;
    return v.f;
}
__device__ __forceinline__ float fast_exp2(float x) {
#if __has_builtin(__builtin_amdgcn_exp2f)
    return __builtin_amdgcn_exp2f(x);
#else
    return exp2f(x);
#endif
}
// async global->LDS, 16B per lane, LDS dest = wave-uniform base + lane*16
__device__ __forceinline__ void load_lds16(const void* g, void* l) {
    auto gp = (__attribute__((address_space(1))) unsigned int*)(uintptr_t)g;
    auto lp = (__attribute__((address_space(3))) unsigned int*)(uintptr_t)l;
    __builtin_amdgcn_global_load_lds(gp, lp, 16, 0, 0);
}

// ---------------- LayerNorm: fp32 in -> bf16 out ----------------
__global__ __launch_bounds__(256) void ln_kernel(const float* __restrict__ X,
        const float* __restrict__ g, const float* __restrict__ b,
        unsigned short* __restrict__ Xn) {
    const int row = blockIdx.x;
    const float* xr = X + (size_t)row * kDM;
    const float4 v0 = ((const float4*)xr)[threadIdx.x];
    const float4 v1 = ((const float4*)xr)[threadIdx.x + 256];
    float s  = v0.x + v0.y + v0.z + v0.w + v1.x + v1.y + v1.z + v1.w;
    float sq = v0.x*v0.x + v0.y*v0.y + v0.z*v0.z + v0.w*v0.w
             + v1.x*v1.x + v1.y*v1.y + v1.z*v1.z + v1.w*v1.w;
    #pragma unroll
    for (int m = 1; m < 64; m <<= 1) { s += __shfl_xor(s, m); sq += __shfl_xor(sq, m); }
    __shared__ float ls[4], lq[4];
    if ((threadIdx.x & 63) == 0) { ls[threadIdx.x >> 6] = s; lq[threadIdx.x >> 6] = sq; }
    __syncthreads();
    s  = ls[0] + ls[1] + ls[2] + ls[3];
    sq = lq[0] + lq[1] + lq[2] + lq[3];
    const float mu   = s * (1.0f / kDM);
    const float rstd = rsqrtf(sq * (1.0f / kDM) - mu * mu + 1e-5f);
    unsigned short* xo = Xn + (size_t)row * kDM;
    {
        const float4 gg = ((const float4*)g)[threadIdx.x];
        const float4 bb = ((const float4*)b)[threadIdx.x];
        ushort4 o;
        o.x = f2bf((v0.x - mu) * rstd * gg.x + bb.x);
        o.y = f2bf((v0.y - mu) * rstd * gg.y + bb.y);
        o.z = f2bf((v0.z - mu) * rstd * gg.z + bb.z);
        o.w = f2bf((v0.w - mu) * rstd * gg.w + bb.w);
        ((ushort4*)xo)[threadIdx.x] = o;
    }
    {
        const float4 gg = ((const float4*)g)[threadIdx.x + 256];
        const float4 bb = ((const float4*)b)[threadIdx.x + 256];
        ushort4 o;
        o.x = f2bf((v1.x - mu) * rstd * gg.x + bb.x);
        o.y = f2bf((v1.y - mu) * rstd * gg.y + bb.y);
        o.z = f2bf((v1.z - mu) * rstd * gg.z + bb.z);
        o.w = f2bf((v1.w - mu) * rstd * gg.w + bb.w);
        ((ushort4*)xo)[threadIdx.x + 256] = o;
    }
}

// ------------- weight transpose+cast: W[K][N] f32 -> Wt[N][K] bf16 -------------
// 64x64 tiles; float4 global reads, odd-stride(65) LDS, 16B coalesced stores.
__global__ __launch_bounds__(256) void wt_kernel(
        const float* __restrict__ W0, const float* __restrict__ W1,
        const float* __restrict__ W2, const float* __restrict__ W3,
        unsigned short* __restrict__ T0, unsigned short* __restrict__ T1,
        unsigned short* __restrict__ T2, unsigned short* __restrict__ T3) {
    const float* W; unsigned short* T;
    switch (blockIdx.z) {
        case 0:  W = W0; T = T0; break;
        case 1:  W = W1; T = T1; break;
        case 2:  W = W2; T = T2; break;
        default: W = W3; T = T3; break;
    }
    __shared__ float tile[64][65];
    const int t = threadIdx.x;
    const int r0 = blockIdx.y * 64, c0 = blockIdx.x * 64;
    const int lr = t >> 4, lc = (t & 15) * 4;
    #pragma unroll
    for (int i = 0; i < 4; ++i) {
        const float4 v = *(const float4*)&W[(size_t)(r0 + lr + i * 16) * kDM + c0 + lc];
        float* tp = &tile[lr + i * 16][lc];
        tp[0] = v.x; tp[1] = v.y; tp[2] = v.z; tp[3] = v.w;
    }
    __syncthreads();
    const int g = t & 7;
    #pragma unroll
    for (int j = 0; j < 2; ++j) {
        const int orr = (t >> 3) + j * 32;
        union { unsigned short u[8]; uint4 v; } o;
        #pragma unroll
        for (int jj = 0; jj < 8; ++jj)
            o.u[jj] = f2bf(tile[g * 8 + jj][orr]);
        *(uint4*)&T[(size_t)(c0 + orr) * kDM + r0 + g * 8] = o.v;
    }
}

// --- bias concat: [bq|bk|bv] -> 6144 floats ---
__global__ __launch_bounds__(256) void bias_pack(const float* __restrict__ bq,
        const float* __restrict__ bk, const float* __restrict__ bv,
        float* __restrict__ o) {
    const int i = blockIdx.x * 256 + threadIdx.x;
    o[i] = (i < 2048) ? bq[i] : ((i < 4096) ? bk[i - 2048] : bv[i - 4096]);
}

// --- V transpose: [bh][s][dh] bf16 -> [bh][dh][s] bf16, 64x64 tiles ---
__global__ __launch_bounds__(256) void vtr_kernel(const unsigned short* __restrict__ Vin,
                                                  unsigned short* __restrict__ Vout) {
    __shared__ __align__(16) unsigned short tile[64 * 72];
    const int bhz = blockIdx.z;
    const int s0 = blockIdx.x * 64, d0 = blockIdx.y * 64;
    const int t = threadIdx.x;
    const unsigned short* src = Vin + ((size_t)bhz * kS + s0) * kDH + d0;
    #pragma unroll
    for (int i = 0; i < 2; ++i) {
        const int r = (t >> 3) + 32 * i;
        const int g = t & 7;
        *(uint4*)(tile + r * 72 + g * 8) = *(const uint4*)(src + (size_t)r * kDH + g * 8);
    }
    __syncthreads();
    unsigned short* dst = Vout + ((size_t)bhz * kDH + d0) * kS + s0;
    #pragma unroll
    for (int i = 0; i < 2; ++i) {
        const int d = (t >> 3) + 32 * i;
        const int sg = t & 7;
        union { unsigned short u[8]; uint4 v; } o;
        #pragma unroll
        for (int j = 0; j < 8; ++j)
            o.u[j] = tile[(sg * 8 + j) * 72 + d];
        *(uint4*)(dst + (size_t)d * kS + sg * 8) = o.v;
    }
}

// ------------- GEMM (legacy 128x128, m97 structure): out-proj only -------------
__global__ __launch_bounds__(256) void gemm_kernel(
        const unsigned short* __restrict__ A, const unsigned short* __restrict__ Bt,
        const float* __restrict__ bias, void* __restrict__ C0, void* __restrict__ C1,
        void* __restrict__ C2, const float scale0, const int fp32out) {
    __shared__ __align__(16) unsigned short ldsA[2][128 * 32];
    __shared__ __align__(16) unsigned short ldsB[2][128 * 32];
    const int m0 = blockIdx.x * 128, n0 = blockIdx.y * 128;
    const int tid = threadIdx.x, lane = tid & 63, w = tid >> 6;
    const int wm = (w >> 1) * 64, wn = (w & 1) * 64;
    const int quad = lane >> 4, l15 = lane & 15;
    f32x4 acc[4][4] = {};
    const int srow = lane >> 2, scol = (lane & 3) * 8;
    for (int k0 = 0; k0 < kDM; k0 += 64) {
        __syncthreads();
        #pragma unroll
        for (int sub = 0; sub < 2; ++sub) {
            #pragma unroll
            for (int i = 0; i < 2; ++i) {
                const int c = w + i * 4;
                const int row = c * 16 + srow;
                const int kc = k0 + sub * 32 + scol;
                load_lds16(A  + (size_t)(m0 + row) * kDM + kc, &ldsA[sub][c * 512]);
                load_lds16(Bt + (size_t)(n0 + row) * kDM + kc, &ldsB[sub][c * 512]);
            }
        }
        __syncthreads();
        #pragma unroll
        for (int sub = 0; sub < 2; ++sub) {
            bf16x8 af[4], bfr[4];
            #pragma unroll
            for (int mt = 0; mt < 4; ++mt)
                af[mt] = *(const bf16x8*)(&ldsA[sub][(wm + mt * 16 + l15) * 32 + quad * 8]);
            #pragma unroll
            for (int nt = 0; nt < 4; ++nt)
                bfr[nt] = *(const bf16x8*)(&ldsB[sub][(wn + nt * 16 + l15) * 32 + quad * 8]);
            #pragma unroll
            for (int mt = 0; mt < 4; ++mt)
                #pragma unroll
                for (int nt = 0; nt < 4; ++nt)
                    acc[mt][nt] = __builtin_amdgcn_mfma_f32_16x16x32_bf16(af[mt], bfr[nt], acc[mt][nt], 0, 0, 0);
        }
    }
    const int proj = n0 >> 11;
    void* Cb = (proj == 0) ? C0 : ((proj == 1) ? C1 : C2);
    const float scl = (proj == 0) ? scale0 : 1.0f;
    #pragma unroll
    for (int mt = 0; mt < 4; ++mt) {
        #pragma unroll
        for (int nt = 0; nt < 4; ++nt) {
            const int ng = n0 + wn + nt * 16 + l15;
            const float bv = bias[ng];
            const int col = ng & 2047;
            const int h = col >> 7, dh = col & 127;
            #pragma unroll
            for (int r = 0; r < 4; ++r) {
                const int mg = m0 + wm + mt * 16 + quad * 4 + r;
                const float val = (acc[mt][nt][r] + bv) * scl;
                if (fp32out) {
                    ((float*)Cb)[(size_t)mg * kDM + ng] = val;
                } else {
                    const int bb = mg >> 11, ss = mg & 2047;
                    ((unsigned short*)Cb)[((size_t)(bb * kNH + h) * kS + ss) * kDH + dh] = f2bf(val);
                }
            }
        }
    }
}

// ------------- GEMM 256x256, 8-wave, BK=32, 2-blocks/CU occupancy pipeline -----
// R5/R6 theory: R2-R4 counters show 1 block/CU (128KB LDS, Occ 16.5%) on a 384-
// block grid = 1.5 rounds -> 75% util ceiling + no co-resident block to hide
// tile-boundary drains. BK=32 halves LDS to 64KB and __launch_bounds__(512,4)
// caps VGPR at 128 -> 2 blocks/CU: all 384 blocks co-resident, tail gone,
// cross-block latency hiding. One __syncthreads per 32-K tile; stage next tile
// FIRST (issue-early), compiler inserts the waitcnt before dependent use.
// LDS swizzle for 64B rows: phys granule = g ^ ((row>>1)&3), applied on inverse-
// swizzled global source + read address (rule 21); per-quad lanes 2/bank = free.
__global__ __launch_bounds__(512, 4) void gemm256_kernel(
        const unsigned short* __restrict__ A, const unsigned short* __restrict__ Bt,
        const float* __restrict__ bias, void* __restrict__ C0, void* __restrict__ C1,
        void* __restrict__ C2, const float scale0) {
    __shared__ __align__(16) unsigned short sA[2][256 * 32];
    __shared__ __align__(16) unsigned short sB[2][256 * 32];
    const int tid = threadIdx.x, lane = tid & 63, w = tid >> 6;
    const int quad = lane >> 4, l15 = lane & 15;
    const int wr = w >> 2, wc = w & 3;          // 2M x 4N wave grid
    const int m0 = blockIdx.x * 256, n0 = blockIdx.y * 256;
    // staging: row = tid>>2, phys granule = tid&3 (linear dest); fetch logical
    // granule (tid&3) ^ ((row>>1)&3) = (tid&3) ^ ((tid>>3)&3)  [row-base 128-mult
    // drops out of (row>>1)&3]
    const int gsrc = ((tid & 3) ^ ((tid >> 3) & 3)) * 8;
    const size_t aSrc0 = (size_t)(m0 + (tid >> 2)) * kDM + gsrc;
    const size_t aSrc1 = aSrc0 + (size_t)128 * kDM;
    const size_t bSrc0 = (size_t)(n0 + (tid >> 2)) * kDM + gsrc;
    const size_t bSrc1 = bSrc0 + (size_t)128 * kDM;
    const int w512 = w * 512;                   // wave's LDS slice (elements)
    // read side: granule = quad ^ ((l15>>1)&3) (base rows are 16-multiples)
    const int colsw = (quad ^ ((l15 >> 1) & 3)) * 8;
    const int aBase = (wr * 128 + l15) * 32 + colsw;
    const int bBase = (wc * 64 + l15) * 32 + colsw;

#define STG(buf, t) { \
    const size_t kk = (size_t)(t) * 32; \
    load_lds16(A  + aSrc0 + kk, &sA[buf][w512]); \
    load_lds16(A  + aSrc1 + kk, &sA[buf][w512 + 4096]); \
    load_lds16(Bt + bSrc0 + kk, &sB[buf][w512]); \
    load_lds16(Bt + bSrc1 + kk, &sB[buf][w512 + 4096]); }

    f32x4 acc[8][4] = {};
    STG(0, 0);
    __syncthreads();                            // vmcnt(0): tile 0 resident

    const int NT = kDM / 32;                    // 64 K-tiles
    for (int t = 0; t < NT; ++t) {
        const int cur = t & 1, nxt = cur ^ 1;
        if (t + 1 < NT) STG(nxt, t + 1);        // issue early; flies under compute
        bf16x8 af[4], bl[4];
        #pragma unroll
        for (int nt = 0; nt < 4; ++nt)
            bl[nt] = *(const bf16x8*)(&sB[cur][bBase + nt * 512]);
        #pragma unroll
        for (int mt = 0; mt < 4; ++mt)
            af[mt] = *(const bf16x8*)(&sA[cur][aBase + mt * 512]);
        __builtin_amdgcn_s_setprio(1);
        #pragma unroll
        for (int mt = 0; mt < 4; ++mt)
            #pragma unroll
            for (int nt = 0; nt < 4; ++nt)
                acc[mt][nt] = __builtin_amdgcn_mfma_f32_16x16x32_bf16(af[mt], bl[nt], acc[mt][nt], 0, 0, 0);
        __builtin_amdgcn_s_setprio(0);
        #pragma unroll
        for (int mt = 0; mt < 4; ++mt)
            af[mt] = *(const bf16x8*)(&sA[cur][aBase + 2048 + mt * 512]);
        __builtin_amdgcn_s_setprio(1);
        #pragma unroll
        for (int mt = 0; mt < 4; ++mt)
            #pragma unroll
            for (int nt = 0; nt < 4; ++nt)
                acc[4 + mt][nt] = __builtin_amdgcn_mfma_f32_16x16x32_bf16(af[mt], bl[nt], acc[4 + mt][nt], 0, 0, 0);
        __builtin_amdgcn_s_setprio(0);
        __syncthreads();                        // drains next-tile stages (vmcnt 0)
    }
#undef STG
    // epilogue: bf16 scatter to [B,H,S,Dh]; scale on proj 0 (Q)
    const int proj = n0 >> 11;
    void* Cb = (proj == 0) ? C0 : ((proj == 1) ? C1 : C2);
    const float scl = (proj == 0) ? scale0 : 1.0f;
    #pragma unroll
    for (int mt = 0; mt < 8; ++mt) {
        #pragma unroll
        for (int nt = 0; nt < 4; ++nt) {
            const int ng = n0 + wc * 64 + nt * 16 + l15;
            const float bv = bias[ng];
            const int col = ng & 2047;
            const int h = col >> 7, dh = col & 127;
            #pragma unroll
            for (int r = 0; r < 4; ++r) {
                const int mg = m0 + wr * 128 + mt * 16 + quad * 4 + r;
                const float val = (acc[mt][nt][r] + bv) * scl;
                const int bb = mg >> 11, ss = mg & 2047;
                ((unsigned short*)Cb)[((size_t)(bb * kNH + h) * kS + ss) * kDH + dh] = f2bf(val);
            }
        }
    }
}

// ------------- causal flash attention, S^T form, paired q-tiles -------------
// (unchanged from R4: dbuf K/V + T13 defer-max + T5 setprio)
__global__ __launch_bounds__(256, 2) void attn_kernel(
        const unsigned short* __restrict__ Q, const unsigned short* __restrict__ Kk,
        const unsigned short* __restrict__ Vt, unsigned short* __restrict__ AV) {
    __shared__ __align__(16) unsigned short ldsK[2][64 * 128];   // swizzled [key][d]
    __shared__ __align__(16) unsigned short ldsV[2][128 * 64];   // swizzled [d][key]
    __shared__ __align__(16) unsigned short ldsP[4 * 16 * 64];   // per-wave swizzled [q][key]
    const int bh = blockIdx.x, pr = blockIdx.y;
    const unsigned short* Qb = Q  + (size_t)bh * kS * kDH;
    const unsigned short* Kb = Kk + (size_t)bh * kS * kDH;
    const unsigned short* Vb = Vt + (size_t)bh * kDH * kS;
    const int tid = threadIdx.x, lane = tid & 63, w = tid >> 6;
    const int quad = lane >> 4, l15 = lane & 15;
    int kSrc[4], vSrc[4], ldst[4];
    #pragma unroll
    for (int i = 0; i < 4; ++i) {
        const int c = w * 4 + i;
        const int rK = c * 4 + (lane >> 4);
        const int gK = (lane & 15) ^ (rK & 15);
        kSrc[i] = rK * kDH + gK * 8;
        const int dV = c * 8 + (lane >> 3);
        const int gV = (lane & 7) ^ (dV & 7);
        vSrc[i] = dV * kS + gV * 8;
        ldst[i] = c * 512;
    }
    unsigned short* pw = ldsP + w * 1024;
    const int pswz = 2 * (l15 & 7);
    const int bb = bh >> 4, h = bh & 15;
    for (int half = 0; half < 2; ++half) {
        const int qt = half ? (31 - pr) : pr;
        const int qrow0 = qt * 64 + w * 16;
        bf16x8 qf[4];
        #pragma unroll
        for (int kk = 0; kk < 4; ++kk)
            qf[kk] = *(const bf16x8*)(Qb + (size_t)(qrow0 + l15) * kDH + kk * 32 + quad * 8);
        f32x4 accO[8] = {};
        float mrun = -3.0e38f, lrun = 0.0f;
        #pragma unroll
        for (int i = 0; i < 4; ++i) {
            load_lds16(Kb + kSrc[i], &ldsK[0][ldst[i]]);
            load_lds16(Vb + vSrc[i], &ldsV[0][ldst[i]]);
        }
        __syncthreads();
        int cur = 0;
        for (int kt = 0; kt <= qt; ++kt) {
            if (kt < qt) {
                #pragma unroll
                for (int i = 0; i < 4; ++i) {
                    load_lds16(Kb + (size_t)(kt + 1) * (64 * kDH) + kSrc[i], &ldsK[cur ^ 1][ldst[i]]);
                    load_lds16(Vb + (kt + 1) * 64 + vSrc[i], &ldsV[cur ^ 1][ldst[i]]);
                }
            }
            f32x4 accS[4] = {};
            __builtin_amdgcn_s_setprio(1);
            #pragma unroll
            for (int kk = 0; kk < 4; ++kk) {
                bf16x8 kf[4];
                #pragma unroll
                for (int mt = 0; mt < 4; ++mt)
                    kf[mt] = *(const bf16x8*)(&ldsK[cur][(mt * 16 + l15) * 128 + (((kk * 4 + quad) ^ l15) << 3)]);
                #pragma unroll
                for (int mt = 0; mt < 4; ++mt)
                    accS[mt] = __builtin_amdgcn_mfma_f32_16x16x32_bf16(kf[mt], qf[kk], accS[mt], 0, 0, 0);
            }
            __builtin_amdgcn_s_setprio(0);
            if (kt == qt) {
                const int ql = w * 16 + l15;
                #pragma unroll
                for (int mt = 0; mt < 4; ++mt)
                    #pragma unroll
                    for (int r = 0; r < 4; ++r)
                        if (mt * 16 + quad * 4 + r > ql) accS[mt][r] = -3.0e38f;
            }
            float mx = accS[0][0];
            #pragma unroll
            for (int mt = 0; mt < 4; ++mt)
                #pragma unroll
                for (int r = 0; r < 4; ++r) mx = fmaxf(mx, accS[mt][r]);
            mx = fmaxf(mx, __shfl_xor(mx, 16));
            mx = fmaxf(mx, __shfl_xor(mx, 32));
            if (!__all(mx - mrun <= 8.0f)) {
                const float mnew = fmaxf(mrun, mx);
                const float al = fast_exp2(mrun - mnew);
                lrun *= al;
                float albr[4];
                #pragma unroll
                for (int r = 0; r < 4; ++r)
                    albr[r] = __shfl(al, (lane & 48) | (quad << 2) | r);
                #pragma unroll
                for (int dt = 0; dt < 8; ++dt)
                    #pragma unroll
                    for (int r = 0; r < 4; ++r)
                        accO[dt][r] *= albr[r];
                mrun = mnew;
            }
            float rs = 0.f;
            #pragma unroll
            for (int mt = 0; mt < 4; ++mt) {
                ushort4 pk;
                unsigned short* pe = (unsigned short*)&pk;
                #pragma unroll
                for (int r = 0; r < 4; ++r) {
                    const float p = fast_exp2(accS[mt][r] - mrun);
                    const unsigned short pb = f2bf(p);
                    pe[r] = pb;
                    rs += bf2f(pb);
                }
                *(ushort4*)(pw + l15 * 64 + (((mt * 4 + quad) ^ pswz) << 2)) = pk;
            }
            rs += __shfl_xor(rs, 16);
            rs += __shfl_xor(rs, 32);
            lrun += rs;
            asm volatile("s_waitcnt lgkmcnt(0)" ::: "memory");
            __builtin_amdgcn_s_setprio(1);
            #pragma unroll
            for (int kk = 0; kk < 2; ++kk) {
                const bf16x8 pa = *(const bf16x8*)(pw + l15 * 64 + (((kk * 8 + quad * 2) ^ pswz) << 2));
                #pragma unroll
                for (int dt = 0; dt < 8; ++dt) {
                    const bf16x8 vf = *(const bf16x8*)(&ldsV[cur][(dt * 16 + l15) * 64 + (((kk * 4 + quad) ^ (l15 & 7)) << 3)]);
                    accO[dt] = __builtin_amdgcn_mfma_f32_16x16x32_bf16(pa, vf, accO[dt], 0, 0, 0);
                }
            }
            __builtin_amdgcn_s_setprio(0);
            __syncthreads();
            cur ^= 1;
        }
        float linv[4];
        #pragma unroll
        for (int r = 0; r < 4; ++r)
            linv[r] = __shfl(lrun, (lane & 48) | (quad << 2) | r);
        #pragma unroll
        for (int r = 0; r < 4; ++r) {
            const float inv = 1.0f / linv[r];
            unsigned short* orow = AV + ((size_t)bb * kS + qrow0 + quad * 4 + r) * kDM + h * kDH;
            #pragma unroll
            for (int dt = 0; dt < 8; ++dt)
                orow[dt * 16 + l15] = f2bf(accO[dt][r] * inv);
        }
    }
}

extern "C" void kernel_launch(void* const* d_in, const int* in_sizes, int n_in,
                              void* d_out, int out_size, void* d_ws, size_t ws_size,
                              hipStream_t stream) {
    const float* X   = (const float*)d_in[0];
    const float* lng = (const float*)d_in[1];
    const float* lnb = (const float*)d_in[2];
    const float* Wq  = (const float*)d_in[3];
    const float* bq  = (const float*)d_in[4];
    const float* Wk  = (const float*)d_in[5];
    const float* bk  = (const float*)d_in[6];
    const float* Wv  = (const float*)d_in[7];
    const float* bv  = (const float*)d_in[8];
    const float* Wo  = (const float*)d_in[9];
    const float* bo  = (const float*)d_in[10];
    float* out = (float*)d_out;

    char* p = (char*)d_ws;
    unsigned short* Xn  = (unsigned short*)p; p += (size_t)kM * kDM * 2;
    unsigned short* Wqt = (unsigned short*)p; p += (size_t)kDM * kDM * 2;  // Wq|Wk|Wv contiguous
    unsigned short* Wkt = (unsigned short*)p; p += (size_t)kDM * kDM * 2;
    unsigned short* Wvt = (unsigned short*)p; p += (size_t)kDM * kDM * 2;
    unsigned short* Wot = (unsigned short*)p; p += (size_t)kDM * kDM * 2;
    unsigned short* Qb  = (unsigned short*)p; p += (size_t)kM * kDM * 2;
    unsigned short* Kb  = (unsigned short*)p; p += (size_t)kM * kDM * 2;
    unsigned short* Vtb = (unsigned short*)p; p += (size_t)kM * kDM * 2;
    unsigned short* AV  = (unsigned short*)p; p += (size_t)kM * kDM * 2;
    unsigned short* Vtmp = AV;        // alias: consumed by vtr before attn writes AV
    float* biasc = (float*)Vtb;       // alias: consumed by qkv-gemm before vtr writes Vtb

    const float qscale = 0.08838834764831845f * 1.4426950408889634f;

    ln_kernel<<<dim3(kM), dim3(256), 0, stream>>>(X, lng, lnb, Xn);
    wt_kernel<<<dim3(32, 32, 4), dim3(256), 0, stream>>>(Wq, Wk, Wv, Wo, Wqt, Wkt, Wvt, Wot);
    bias_pack<<<dim3(24), dim3(256), 0, stream>>>(bq, bk, bv, biasc);
    // fused QKV GEMM: 256x256 8-wave BK=32 2-blocks/CU; N=6144 over [Wqt|Wkt|Wvt]
    gemm256_kernel<<<dim3(16, 24), dim3(512), 0, stream>>>(Xn, Wqt, biasc, Qb, Kb, Vtmp, qscale);
    vtr_kernel<<<dim3(32, 2, 32), dim3(256), 0, stream>>>(Vtmp, Vtb);
    attn_kernel<<<dim3(32, 16), dim3(256), 0, stream>>>(Qb, Kb, Vtb, AV);
    gemm_kernel<<<dim3(32, 16), dim3(256), 0, stream>>>(AV, Wot, bo, out, out, out, 1.0f, 1);
}

// Round 8
// 384.815 us; speedup vs baseline: 2.3628x; 2.3628x over previous
//
#include <hip/hip_runtime.h>
#include <cstdint>

constexpr int kDM = 2048;   // d_model
constexpr int kNH = 16;     // heads
constexpr int kDH = 128;    // head dim
constexpr int kS  = 2048;   // seq
constexpr int kM  = 4096;   // B*S rows

typedef __bf16 bf16x8 __attribute__((ext_vector_type(8)));
typedef float  f32x4  __attribute__((ext_vector_type(4)));

__device__ __forceinline__ unsigned short f2bf(float f) {
    union { float f; unsigned u; } v; v.f = f;
    unsigned u = v.u;
    u += 0x7fffu + ((u >> 16) & 1u);   // RNE
    return (unsigned short)(u >> 16);
}
__device__ __forceinline__ float bf2f(unsigned short b) {
    union { unsigned u; float f; } v; v.u = ((unsigned)b) << 16;
    return v.f;
}
__device__ __forceinline__ float fast_exp2(float x) {
#if __has_builtin(__builtin_amdgcn_exp2f)
    return __builtin_amdgcn_exp2f(x);
#else
    return exp2f(x);
#endif
}
// async global->LDS, 16B per lane, LDS dest = wave-uniform base + lane*16
__device__ __forceinline__ void load_lds16(const void* g, void* l) {
    auto gp = (__attribute__((address_space(1))) unsigned int*)(uintptr_t)g;
    auto lp = (__attribute__((address_space(3))) unsigned int*)(uintptr_t)l;
    __builtin_amdgcn_global_load_lds(gp, lp, 16, 0, 0);
}

// ---------------- LayerNorm: fp32 in -> bf16 out ----------------
__global__ __launch_bounds__(256) void ln_kernel(const float* __restrict__ X,
        const float* __restrict__ g, const float* __restrict__ b,
        unsigned short* __restrict__ Xn) {
    const int row = blockIdx.x;
    const float* xr = X + (size_t)row * kDM;
    const float4 v0 = ((const float4*)xr)[threadIdx.x];
    const float4 v1 = ((const float4*)xr)[threadIdx.x + 256];
    float s  = v0.x + v0.y + v0.z + v0.w + v1.x + v1.y + v1.z + v1.w;
    float sq = v0.x*v0.x + v0.y*v0.y + v0.z*v0.z + v0.w*v0.w
             + v1.x*v1.x + v1.y*v1.y + v1.z*v1.z + v1.w*v1.w;
    #pragma unroll
    for (int m = 1; m < 64; m <<= 1) { s += __shfl_xor(s, m); sq += __shfl_xor(sq, m); }
    __shared__ float ls[4], lq[4];
    if ((threadIdx.x & 63) == 0) { ls[threadIdx.x >> 6] = s; lq[threadIdx.x >> 6] = sq; }
    __syncthreads();
    s  = ls[0] + ls[1] + ls[2] + ls[3];
    sq = lq[0] + lq[1] + lq[2] + lq[3];
    const float mu   = s * (1.0f / kDM);
    const float rstd = rsqrtf(sq * (1.0f / kDM) - mu * mu + 1e-5f);
    unsigned short* xo = Xn + (size_t)row * kDM;
    {
        const float4 gg = ((const float4*)g)[threadIdx.x];
        const float4 bb = ((const float4*)b)[threadIdx.x];
        ushort4 o;
        o.x = f2bf((v0.x - mu) * rstd * gg.x + bb.x);
        o.y = f2bf((v0.y - mu) * rstd * gg.y + bb.y);
        o.z = f2bf((v0.z - mu) * rstd * gg.z + bb.z);
        o.w = f2bf((v0.w - mu) * rstd * gg.w + bb.w);
        ((ushort4*)xo)[threadIdx.x] = o;
    }
    {
        const float4 gg = ((const float4*)g)[threadIdx.x + 256];
        const float4 bb = ((const float4*)b)[threadIdx.x + 256];
        ushort4 o;
        o.x = f2bf((v1.x - mu) * rstd * gg.x + bb.x);
        o.y = f2bf((v1.y - mu) * rstd * gg.y + bb.y);
        o.z = f2bf((v1.z - mu) * rstd * gg.z + bb.z);
        o.w = f2bf((v1.w - mu) * rstd * gg.w + bb.w);
        ((ushort4*)xo)[threadIdx.x + 256] = o;
    }
}

// ------------- weight transpose+cast: W[K][N] f32 -> Wt[N][K] bf16 -------------
// 64x64 tiles; float4 global reads, odd-stride(65) LDS, 16B coalesced stores.
__global__ __launch_bounds__(256) void wt_kernel(
        const float* __restrict__ W0, const float* __restrict__ W1,
        const float* __restrict__ W2, const float* __restrict__ W3,
        unsigned short* __restrict__ T0, unsigned short* __restrict__ T1,
        unsigned short* __restrict__ T2, unsigned short* __restrict__ T3) {
    const float* W; unsigned short* T;
    switch (blockIdx.z) {
        case 0:  W = W0; T = T0; break;
        case 1:  W = W1; T = T1; break;
        case 2:  W = W2; T = T2; break;
        default: W = W3; T = T3; break;
    }
    __shared__ float tile[64][65];
    const int t = threadIdx.x;
    const int r0 = blockIdx.y * 64, c0 = blockIdx.x * 64;
    const int lr = t >> 4, lc = (t & 15) * 4;
    #pragma unroll
    for (int i = 0; i < 4; ++i) {
        const float4 v = *(const float4*)&W[(size_t)(r0 + lr + i * 16) * kDM + c0 + lc];
        float* tp = &tile[lr + i * 16][lc];
        tp[0] = v.x; tp[1] = v.y; tp[2] = v.z; tp[3] = v.w;
    }
    __syncthreads();
    const int g = t & 7;
    #pragma unroll
    for (int j = 0; j < 2; ++j) {
        const int orr = (t >> 3) + j * 32;
        union { unsigned short u[8]; uint4 v; } o;
        #pragma unroll
        for (int jj = 0; jj < 8; ++jj)
            o.u[jj] = f2bf(tile[g * 8 + jj][orr]);
        *(uint4*)&T[(size_t)(c0 + orr) * kDM + r0 + g * 8] = o.v;
    }
}

// --- bias concat: [bq|bk|bv] -> 6144 floats ---
__global__ __launch_bounds__(256) void bias_pack(const float* __restrict__ bq,
        const float* __restrict__ bk, const float* __restrict__ bv,
        float* __restrict__ o) {
    const int i = blockIdx.x * 256 + threadIdx.x;
    o[i] = (i < 2048) ? bq[i] : ((i < 4096) ? bk[i - 2048] : bv[i - 4096]);
}

// --- V transpose: [bh][s][dh] bf16 -> [bh][dh][s] bf16, 64x64 tiles ---
__global__ __launch_bounds__(256) void vtr_kernel(const unsigned short* __restrict__ Vin,
                                                  unsigned short* __restrict__ Vout) {
    __shared__ __align__(16) unsigned short tile[64 * 72];
    const int bhz = blockIdx.z;
    const int s0 = blockIdx.x * 64, d0 = blockIdx.y * 64;
    const int t = threadIdx.x;
    const unsigned short* src = Vin + ((size_t)bhz * kS + s0) * kDH + d0;
    #pragma unroll
    for (int i = 0; i < 2; ++i) {
        const int r = (t >> 3) + 32 * i;
        const int g = t & 7;
        *(uint4*)(tile + r * 72 + g * 8) = *(const uint4*)(src + (size_t)r * kDH + g * 8);
    }
    __syncthreads();
    unsigned short* dst = Vout + ((size_t)bhz * kDH + d0) * kS + s0;
    #pragma unroll
    for (int i = 0; i < 2; ++i) {
        const int d = (t >> 3) + 32 * i;
        const int sg = t & 7;
        union { unsigned short u[8]; uint4 v; } o;
        #pragma unroll
        for (int j = 0; j < 8; ++j)
            o.u[j] = tile[(sg * 8 + j) * 72 + d];
        *(uint4*)(dst + (size_t)d * kS + sg * 8) = o.v;
    }
}

// ------------- GEMM (legacy 128x128, m97 structure): out-proj only -------------
__global__ __launch_bounds__(256) void gemm_kernel(
        const unsigned short* __restrict__ A, const unsigned short* __restrict__ Bt,
        const float* __restrict__ bias, void* __restrict__ C0, void* __restrict__ C1,
        void* __restrict__ C2, const float scale0, const int fp32out) {
    __shared__ __align__(16) unsigned short ldsA[2][128 * 32];
    __shared__ __align__(16) unsigned short ldsB[2][128 * 32];
    const int m0 = blockIdx.x * 128, n0 = blockIdx.y * 128;
    const int tid = threadIdx.x, lane = tid & 63, w = tid >> 6;
    const int wm = (w >> 1) * 64, wn = (w & 1) * 64;
    const int quad = lane >> 4, l15 = lane & 15;
    f32x4 acc[4][4] = {};
    const int srow = lane >> 2, scol = (lane & 3) * 8;
    for (int k0 = 0; k0 < kDM; k0 += 64) {
        __syncthreads();
        #pragma unroll
        for (int sub = 0; sub < 2; ++sub) {
            #pragma unroll
            for (int i = 0; i < 2; ++i) {
                const int c = w + i * 4;
                const int row = c * 16 + srow;
                const int kc = k0 + sub * 32 + scol;
                load_lds16(A  + (size_t)(m0 + row) * kDM + kc, &ldsA[sub][c * 512]);
                load_lds16(Bt + (size_t)(n0 + row) * kDM + kc, &ldsB[sub][c * 512]);
            }
        }
        __syncthreads();
        #pragma unroll
        for (int sub = 0; sub < 2; ++sub) {
            bf16x8 af[4], bfr[4];
            #pragma unroll
            for (int mt = 0; mt < 4; ++mt)
                af[mt] = *(const bf16x8*)(&ldsA[sub][(wm + mt * 16 + l15) * 32 + quad * 8]);
            #pragma unroll
            for (int nt = 0; nt < 4; ++nt)
                bfr[nt] = *(const bf16x8*)(&ldsB[sub][(wn + nt * 16 + l15) * 32 + quad * 8]);
            #pragma unroll
            for (int mt = 0; mt < 4; ++mt)
                #pragma unroll
                for (int nt = 0; nt < 4; ++nt)
                    acc[mt][nt] = __builtin_amdgcn_mfma_f32_16x16x32_bf16(af[mt], bfr[nt], acc[mt][nt], 0, 0, 0);
        }
    }
    const int proj = n0 >> 11;
    void* Cb = (proj == 0) ? C0 : ((proj == 1) ? C1 : C2);
    const float scl = (proj == 0) ? scale0 : 1.0f;
    #pragma unroll
    for (int mt = 0; mt < 4; ++mt) {
        #pragma unroll
        for (int nt = 0; nt < 4; ++nt) {
            const int ng = n0 + wn + nt * 16 + l15;
            const float bv = bias[ng];
            const int col = ng & 2047;
            const int h = col >> 7, dh = col & 127;
            #pragma unroll
            for (int r = 0; r < 4; ++r) {
                const int mg = m0 + wm + mt * 16 + quad * 4 + r;
                const float val = (acc[mt][nt][r] + bv) * scl;
                if (fp32out) {
                    ((float*)Cb)[(size_t)mg * kDM + ng] = val;
                } else {
                    const int bb = mg >> 11, ss = mg & 2047;
                    ((unsigned short*)Cb)[((size_t)(bb * kNH + h) * kS + ss) * kDH + dh] = f2bf(val);
                }
            }
        }
    }
}

// ------------- GEMM 256x256, 8-wave, BK=64, 4-phase counted-vmcnt pipeline -----
// R7/R8: exact R2/R4 structure (proven 121.8us, VGPR 120, 0 bank conflicts).
// R6 lesson: 256^2 tile REQUIRES >128 VGPR (acc alone = 128); launch_bounds
// caps below that spill the accumulator to scratch (WRITE 1.8GB). Do not retry.
__global__ __launch_bounds__(512, 2) void gemm256_kernel(
        const unsigned short* __restrict__ A, const unsigned short* __restrict__ Bt,
        const float* __restrict__ bias, void* __restrict__ C0, void* __restrict__ C1,
        void* __restrict__ C2, const float scale0) {
    __shared__ __align__(16) unsigned short sA[2][2 * 128 * 64];
    __shared__ __align__(16) unsigned short sB[2][2 * 128 * 64];
    const int tid = threadIdx.x, lane = tid & 63, w = tid >> 6;
    const int quad = lane >> 4, l15 = lane & 15;
    const int wr = w >> 2, wc = w & 3;          // 2M x 4N wave grid
    const int m0 = blockIdx.x * 256, n0 = blockIdx.y * 256;
    const int srow = lane >> 3;
    const int scol = ((lane & 7) ^ srow) * 8;   // inverse-swizzled global source
    size_t aOff[2], bOff[2]; int lOff[2];
    #pragma unroll
    for (int i = 0; i < 2; ++i) {
        const int wrow = (i * 8 + w) * 8 + srow;     // row within a 128-row half
        aOff[i] = (size_t)(m0 + wrow) * kDM + scol;  // + h*128*kDM + kt*64
        bOff[i] = (size_t)(n0 + wrow) * kDM + scol;
        lOff[i] = (i * 8 + w) * 512;                 // + h*8192 (elements)
    }
    const int swz = l15 & 7;
    int colq[2];
    #pragma unroll
    for (int ks = 0; ks < 2; ++ks) colq[ks] = ((ks * 4 + quad) ^ swz) * 8;

#define STG_A(buf, h, kt) { \
    load_lds16(A  + aOff[0] + (size_t)(h) * (128 * kDM) + (kt) * 64, &sA[buf][(h) * 8192 + lOff[0]]); \
    load_lds16(A  + aOff[1] + (size_t)(h) * (128 * kDM) + (kt) * 64, &sA[buf][(h) * 8192 + lOff[1]]); }
#define STG_B(buf, h, kt) { \
    load_lds16(Bt + bOff[0] + (size_t)(h) * (128 * kDM) + (kt) * 64, &sB[buf][(h) * 8192 + lOff[0]]); \
    load_lds16(Bt + bOff[1] + (size_t)(h) * (128 * kDM) + (kt) * 64, &sB[buf][(h) * 8192 + lOff[1]]); }

    f32x4 acc[8][4] = {};
    STG_A(0, 0, 0); STG_A(0, 1, 0);
    STG_B(0, 0, 0); STG_B(0, 1, 0);
    STG_B(1, 0, 1); STG_A(1, 0, 1);
    asm volatile("s_waitcnt vmcnt(4)" ::: "memory");
    __builtin_amdgcn_s_barrier();

    const int NT = kDM / 64;                    // 32 K-tiles
    bf16x8 af[4][2], bl[2][2], bh[2][2];
    for (int t = 0; t < NT; ++t) {
        const int cur = t & 1, nxt = cur ^ 1;
        // ---- phase 1: A-lo + B-lo reads; stage B1^{t+1}; mfma (m-lo x n-lo)
        #pragma unroll
        for (int mt = 0; mt < 4; ++mt)
            #pragma unroll
            for (int ks = 0; ks < 2; ++ks)
                af[mt][ks] = *(const bf16x8*)(&sA[cur][(wr * 128 + mt * 16 + l15) * 64 + colq[ks]]);
        #pragma unroll
        for (int nt = 0; nt < 2; ++nt)
            #pragma unroll
            for (int ks = 0; ks < 2; ++ks)
                bl[nt][ks] = *(const bf16x8*)(&sB[cur][(wc * 64 + nt * 16 + l15) * 64 + colq[ks]]);
        if (t + 1 < NT) STG_B(nxt, 1, t + 1);
        __builtin_amdgcn_s_barrier();
        asm volatile("s_waitcnt lgkmcnt(0)" ::: "memory");
        __builtin_amdgcn_s_setprio(1);
        #pragma unroll
        for (int mt = 0; mt < 4; ++mt)
            #pragma unroll
            for (int nt = 0; nt < 2; ++nt)
                #pragma unroll
                for (int ks = 0; ks < 2; ++ks)
                    acc[mt][nt] = __builtin_amdgcn_mfma_f32_16x16x32_bf16(af[mt][ks], bl[nt][ks], acc[mt][nt], 0, 0, 0);
        __builtin_amdgcn_s_setprio(0);
        __builtin_amdgcn_s_barrier();
        // ---- phase 2: B-hi reads; stage A1^{t+1}; mfma (m-lo x n-hi)
        #pragma unroll
        for (int nt = 0; nt < 2; ++nt)
            #pragma unroll
            for (int ks = 0; ks < 2; ++ks)
                bh[nt][ks] = *(const bf16x8*)(&sB[cur][(wc * 64 + 32 + nt * 16 + l15) * 64 + colq[ks]]);
        if (t + 1 < NT) STG_A(nxt, 1, t + 1);
        __builtin_amdgcn_s_barrier();
        asm volatile("s_waitcnt lgkmcnt(0)" ::: "memory");
        __builtin_amdgcn_s_setprio(1);
        #pragma unroll
        for (int mt = 0; mt < 4; ++mt)
            #pragma unroll
            for (int nt = 0; nt < 2; ++nt)
                #pragma unroll
                for (int ks = 0; ks < 2; ++ks)
                    acc[mt][2 + nt] = __builtin_amdgcn_mfma_f32_16x16x32_bf16(af[mt][ks], bh[nt][ks], acc[mt][2 + nt], 0, 0, 0);
        __builtin_amdgcn_s_setprio(0);
        __builtin_amdgcn_s_barrier();
        // ---- phase 3: A-hi reads (reuse af regs); stage B0^{t+2}; mfma (m-hi x n-hi)
        #pragma unroll
        for (int mt = 0; mt < 4; ++mt)
            #pragma unroll
            for (int ks = 0; ks < 2; ++ks)
                af[mt][ks] = *(const bf16x8*)(&sA[cur][(wr * 128 + 64 + mt * 16 + l15) * 64 + colq[ks]]);
        if (t + 2 < NT) STG_B(cur, 0, t + 2);
        __builtin_amdgcn_s_barrier();
        asm volatile("s_waitcnt lgkmcnt(0)" ::: "memory");
        __builtin_amdgcn_s_setprio(1);
        #pragma unroll
        for (int mt = 0; mt < 4; ++mt)
            #pragma unroll
            for (int nt = 0; nt < 2; ++nt)
                #pragma unroll
                for (int ks = 0; ks < 2; ++ks)
                    acc[4 + mt][2 + nt] = __builtin_amdgcn_mfma_f32_16x16x32_bf16(af[mt][ks], bh[nt][ks], acc[4 + mt][2 + nt], 0, 0, 0);
        __builtin_amdgcn_s_setprio(0);
        __builtin_amdgcn_s_barrier();
        // ---- phase 4: regs only; stage A0^{t+2}; mfma (m-hi x n-lo); boundary
        if (t + 2 < NT) STG_A(cur, 0, t + 2);
        __builtin_amdgcn_s_barrier();
        __builtin_amdgcn_s_setprio(1);
        #pragma unroll
        for (int mt = 0; mt < 4; ++mt)
            #pragma unroll
            for (int nt = 0; nt < 2; ++nt)
                #pragma unroll
                for (int ks = 0; ks < 2; ++ks)
                    acc[4 + mt][nt] = __builtin_amdgcn_mfma_f32_16x16x32_bf16(af[mt][ks], bl[nt][ks], acc[4 + mt][nt], 0, 0, 0);
        __builtin_amdgcn_s_setprio(0);
        if (t + 1 < NT) {
            if (t + 2 < NT) { asm volatile("s_waitcnt vmcnt(4)" ::: "memory"); }
            else            { asm volatile("s_waitcnt vmcnt(0)" ::: "memory"); }
            __builtin_amdgcn_s_barrier();
        }
    }
#undef STG_A
#undef STG_B
    const int proj = n0 >> 11;
    void* Cb = (proj == 0) ? C0 : ((proj == 1) ? C1 : C2);
    const float scl = (proj == 0) ? scale0 : 1.0f;
    #pragma unroll
    for (int mt = 0; mt < 8; ++mt) {
        #pragma unroll
        for (int nt = 0; nt < 4; ++nt) {
            const int ng = n0 + wc * 64 + nt * 16 + l15;
            const float bv = bias[ng];
            const int col = ng & 2047;
            const int h = col >> 7, dh = col & 127;
            #pragma unroll
            for (int r = 0; r < 4; ++r) {
                const int mg = m0 + wr * 128 + mt * 16 + quad * 4 + r;
                const float val = (acc[mt][nt][r] + bv) * scl;
                const int bb = mg >> 11, ss = mg & 2047;
                ((unsigned short*)Cb)[((size_t)(bb * kNH + h) * kS + ss) * kDH + dh] = f2bf(val);
            }
        }
    }
}

// ------------- causal flash attention, dual q-tile blocks -------------
// R7/R8: block = 512 threads (8 waves) owning q-tiles 2pr (waves 0-3) and
// 2pr+1 (waves 4-7); K/V staged ONCE per key-tile for both -> K/V re-read per
// head drops 16x -> 8x (total ~540MB -> ~280MB). Theory: attn is BW-
// amplification-bound (inferred ~110-120us vs ~20us compute). Loop bound
// kt<=2pr+1 is block-uniform (barrier-safe); tile-A waves skip compute (wave-
// uniform branch, no barriers inside) on the final iter only.
__global__ __launch_bounds__(512, 2) void attn_kernel(
        const unsigned short* __restrict__ Q, const unsigned short* __restrict__ Kk,
        const unsigned short* __restrict__ Vt, unsigned short* __restrict__ AV) {
    __shared__ __align__(16) unsigned short ldsK[2][64 * 128];   // swizzled [key][d]
    __shared__ __align__(16) unsigned short ldsV[2][128 * 64];   // swizzled [d][key]
    __shared__ __align__(16) unsigned short ldsP[8 * 16 * 64];   // per-wave swizzled [q][key]
    const int bh = blockIdx.x, pr = blockIdx.y;
    const unsigned short* Qb = Q  + (size_t)bh * kS * kDH;
    const unsigned short* Kb = Kk + (size_t)bh * kS * kDH;
    const unsigned short* Vb = Vt + (size_t)bh * kDH * kS;
    const int tid = threadIdx.x, lane = tid & 63, w = tid >> 6;
    const int quad = lane >> 4, l15 = lane & 15;
    const int wlocal = w & 3, hf = w >> 2;
    const int qt = 2 * pr + hf;                 // this wave's q-tile
    const int ktMax = 2 * pr + 1;               // block-uniform key-tile bound
    // staging offsets: 8 waves x 2 chunks cover c=0..15 (source-swizzled)
    int kSrc[2], vSrc[2], ldst[2];
    #pragma unroll
    for (int i = 0; i < 2; ++i) {
        const int c = w * 2 + i;
        const int rK = c * 4 + (lane >> 4);
        const int gK = (lane & 15) ^ (rK & 15);
        kSrc[i] = rK * kDH + gK * 8;
        const int dV = c * 8 + (lane >> 3);
        const int gV = (lane & 7) ^ (dV & 7);
        vSrc[i] = dV * kS + gV * 8;
        ldst[i] = c * 512;
    }
    unsigned short* pw = ldsP + w * 1024;
    const int pswz = 2 * (l15 & 7);
    const int bb = bh >> 4, h = bh & 15;

    const int qrow0 = qt * 64 + wlocal * 16;    // wave owns 16 q-rows
    bf16x8 qf[4];
    #pragma unroll
    for (int kk = 0; kk < 4; ++kk)
        qf[kk] = *(const bf16x8*)(Qb + (size_t)(qrow0 + l15) * kDH + kk * 32 + quad * 8);
    f32x4 accO[8] = {};
    float mrun = -3.0e38f, lrun = 0.0f;
    #pragma unroll
    for (int i = 0; i < 2; ++i) {
        load_lds16(Kb + kSrc[i], &ldsK[0][ldst[i]]);
        load_lds16(Vb + vSrc[i], &ldsV[0][ldst[i]]);
    }
    __syncthreads();                            // tile 0 resident
    int cur = 0;
    for (int kt = 0; kt <= ktMax; ++kt) {
        if (kt < ktMax) {                       // prefetch next K/V tile
            #pragma unroll
            for (int i = 0; i < 2; ++i) {
                load_lds16(Kb + (size_t)(kt + 1) * (64 * kDH) + kSrc[i], &ldsK[cur ^ 1][ldst[i]]);
                load_lds16(Vb + (kt + 1) * 64 + vSrc[i], &ldsV[cur ^ 1][ldst[i]]);
            }
        }
        if (kt <= qt) {                         // wave-uniform: tile-A waves skip last iter
            f32x4 accS[4] = {};
            __builtin_amdgcn_s_setprio(1);
            #pragma unroll
            for (int kk = 0; kk < 4; ++kk) {
                bf16x8 kf[4];
                #pragma unroll
                for (int mt = 0; mt < 4; ++mt)
                    kf[mt] = *(const bf16x8*)(&ldsK[cur][(mt * 16 + l15) * 128 + (((kk * 4 + quad) ^ l15) << 3)]);
                #pragma unroll
                for (int mt = 0; mt < 4; ++mt)
                    accS[mt] = __builtin_amdgcn_mfma_f32_16x16x32_bf16(kf[mt], qf[kk], accS[mt], 0, 0, 0);
            }
            __builtin_amdgcn_s_setprio(0);
            if (kt == qt) {
                const int ql = wlocal * 16 + l15;
                #pragma unroll
                for (int mt = 0; mt < 4; ++mt)
                    #pragma unroll
                    for (int r = 0; r < 4; ++r)
                        if (mt * 16 + quad * 4 + r > ql) accS[mt][r] = -3.0e38f;
            }
            float mx = accS[0][0];
            #pragma unroll
            for (int mt = 0; mt < 4; ++mt)
                #pragma unroll
                for (int r = 0; r < 4; ++r) mx = fmaxf(mx, accS[mt][r]);
            mx = fmaxf(mx, __shfl_xor(mx, 16));
            mx = fmaxf(mx, __shfl_xor(mx, 32));
            if (!__all(mx - mrun <= 8.0f)) {    // T13 defer-max
                const float mnew = fmaxf(mrun, mx);
                const float al = fast_exp2(mrun - mnew);
                lrun *= al;
                float albr[4];
                #pragma unroll
                for (int r = 0; r < 4; ++r)
                    albr[r] = __shfl(al, (lane & 48) | (quad << 2) | r);
                #pragma unroll
                for (int dt = 0; dt < 8; ++dt)
                    #pragma unroll
                    for (int r = 0; r < 4; ++r)
                        accO[dt][r] *= albr[r];
                mrun = mnew;
            }
            float rs = 0.f;
            #pragma unroll
            for (int mt = 0; mt < 4; ++mt) {
                ushort4 pk;
                unsigned short* pe = (unsigned short*)&pk;
                #pragma unroll
                for (int r = 0; r < 4; ++r) {
                    const float p = fast_exp2(accS[mt][r] - mrun);
                    const unsigned short pb = f2bf(p);
                    pe[r] = pb;
                    rs += bf2f(pb);
                }
                *(ushort4*)(pw + l15 * 64 + (((mt * 4 + quad) ^ pswz) << 2)) = pk;
            }
            rs += __shfl_xor(rs, 16);
            rs += __shfl_xor(rs, 32);
            lrun += rs;
            asm volatile("s_waitcnt lgkmcnt(0)" ::: "memory");  // P visible to own wave
            __builtin_amdgcn_s_setprio(1);
            #pragma unroll
            for (int kk = 0; kk < 2; ++kk) {
                const bf16x8 pa = *(const bf16x8*)(pw + l15 * 64 + (((kk * 8 + quad * 2) ^ pswz) << 2));
                #pragma unroll
                for (int dt = 0; dt < 8; ++dt) {
                    const bf16x8 vf = *(const bf16x8*)(&ldsV[cur][(dt * 16 + l15) * 64 + (((kk * 4 + quad) ^ (l15 & 7)) << 3)]);
                    accO[dt] = __builtin_amdgcn_mfma_f32_16x16x32_bf16(pa, vf, accO[dt], 0, 0, 0);
                }
            }
            __builtin_amdgcn_s_setprio(0);
        }
        __syncthreads();                        // block-uniform; drains prefetch
        cur ^= 1;
    }
    float linv[4];
    #pragma unroll
    for (int r = 0; r < 4; ++r)
        linv[r] = __shfl(lrun, (lane & 48) | (quad << 2) | r);
    #pragma unroll
    for (int r = 0; r < 4; ++r) {
        const float inv = 1.0f / linv[r];
        unsigned short* orow = AV + ((size_t)bb * kS + qrow0 + quad * 4 + r) * kDM + h * kDH;
        #pragma unroll
        for (int dt = 0; dt < 8; ++dt)
            orow[dt * 16 + l15] = f2bf(accO[dt][r] * inv);
    }
}

extern "C" void kernel_launch(void* const* d_in, const int* in_sizes, int n_in,
                              void* d_out, int out_size, void* d_ws, size_t ws_size,
                              hipStream_t stream) {
    const float* X   = (const float*)d_in[0];
    const float* lng = (const float*)d_in[1];
    const float* lnb = (const float*)d_in[2];
    const float* Wq  = (const float*)d_in[3];
    const float* bq  = (const float*)d_in[4];
    const float* Wk  = (const float*)d_in[5];
    const float* bk  = (const float*)d_in[6];
    const float* Wv  = (const float*)d_in[7];
    const float* bv  = (const float*)d_in[8];
    const float* Wo  = (const float*)d_in[9];
    const float* bo  = (const float*)d_in[10];
    float* out = (float*)d_out;

    char* p = (char*)d_ws;
    unsigned short* Xn  = (unsigned short*)p; p += (size_t)kM * kDM * 2;
    unsigned short* Wqt = (unsigned short*)p; p += (size_t)kDM * kDM * 2;  // Wq|Wk|Wv contiguous
    unsigned short* Wkt = (unsigned short*)p; p += (size_t)kDM * kDM * 2;
    unsigned short* Wvt = (unsigned short*)p; p += (size_t)kDM * kDM * 2;
    unsigned short* Wot = (unsigned short*)p; p += (size_t)kDM * kDM * 2;
    unsigned short* Qb  = (unsigned short*)p; p += (size_t)kM * kDM * 2;
    unsigned short* Kb  = (unsigned short*)p; p += (size_t)kM * kDM * 2;
    unsigned short* Vtb = (unsigned short*)p; p += (size_t)kM * kDM * 2;
    unsigned short* AV  = (unsigned short*)p; p += (size_t)kM * kDM * 2;
    unsigned short* Vtmp = AV;        // alias: consumed by vtr before attn writes AV
    float* biasc = (float*)Vtb;       // alias: consumed by qkv-gemm before vtr writes Vtb

    const float qscale = 0.08838834764831845f * 1.4426950408889634f;

    ln_kernel<<<dim3(kM), dim3(256), 0, stream>>>(X, lng, lnb, Xn);
    wt_kernel<<<dim3(32, 32, 4), dim3(256), 0, stream>>>(Wq, Wk, Wv, Wo, Wqt, Wkt, Wvt, Wot);
    bias_pack<<<dim3(24), dim3(256), 0, stream>>>(bq, bk, bv, biasc);
    // fused QKV GEMM: 256x256 8-wave counted-vmcnt pipeline; N=6144 over [Wqt|Wkt|Wvt]
    gemm256_kernel<<<dim3(16, 24), dim3(512), 0, stream>>>(Xn, Wqt, biasc, Qb, Kb, Vtmp, qscale);
    vtr_kernel<<<dim3(32, 2, 32), dim3(256), 0, stream>>>(Vtmp, Vtb);
    attn_kernel<<<dim3(32, 16), dim3(512), 0, stream>>>(Qb, Kb, Vtb, AV);
    gemm_kernel<<<dim3(32, 16), dim3(256), 0, stream>>>(AV, Wot, bo, out, out, out, 1.0f, 1);
}

// Round 10
// 380.936 us; speedup vs baseline: 2.3869x; 1.0102x over previous
//
#include <hip/hip_runtime.h>
#include <cstdint>

constexpr int kDM = 2048;   // d_model
constexpr int kNH = 16;     // heads
constexpr int kDH = 128;    // head dim
constexpr int kS  = 2048;   // seq
constexpr int kM  = 4096;   // B*S rows

typedef __bf16 bf16x8 __attribute__((ext_vector_type(8)));
typedef float  f32x4  __attribute__((ext_vector_type(4)));

__device__ __forceinline__ unsigned short f2bf(float f) {
    union { float f; unsigned u; } v; v.f = f;
    unsigned u = v.u;
    u += 0x7fffu + ((u >> 16) & 1u);   // RNE
    return (unsigned short)(u >> 16);
}
__device__ __forceinline__ float bf2f(unsigned short b) {
    union { unsigned u; float f; } v; v.u = ((unsigned)b) << 16;
    return v.f;
}
__device__ __forceinline__ float fast_exp2(float x) {
#if __has_builtin(__builtin_amdgcn_exp2f)
    return __builtin_amdgcn_exp2f(x);
#else
    return exp2f(x);
#endif
}
// async global->LDS, 16B per lane, LDS dest = wave-uniform base + lane*16
__device__ __forceinline__ void load_lds16(const void* g, void* l) {
    auto gp = (__attribute__((address_space(1))) unsigned int*)(uintptr_t)g;
    auto lp = (__attribute__((address_space(3))) unsigned int*)(uintptr_t)l;
    __builtin_amdgcn_global_load_lds(gp, lp, 16, 0, 0);
}

// ---------------- LayerNorm: fp32 in -> bf16 out ----------------
__global__ __launch_bounds__(256) void ln_kernel(const float* __restrict__ X,
        const float* __restrict__ g, const float* __restrict__ b,
        unsigned short* __restrict__ Xn) {
    const int row = blockIdx.x;
    const float* xr = X + (size_t)row * kDM;
    const float4 v0 = ((const float4*)xr)[threadIdx.x];
    const float4 v1 = ((const float4*)xr)[threadIdx.x + 256];
    float s  = v0.x + v0.y + v0.z + v0.w + v1.x + v1.y + v1.z + v1.w;
    float sq = v0.x*v0.x + v0.y*v0.y + v0.z*v0.z + v0.w*v0.w
             + v1.x*v1.x + v1.y*v1.y + v1.z*v1.z + v1.w*v1.w;
    #pragma unroll
    for (int m = 1; m < 64; m <<= 1) { s += __shfl_xor(s, m); sq += __shfl_xor(sq, m); }
    __shared__ float ls[4], lq[4];
    if ((threadIdx.x & 63) == 0) { ls[threadIdx.x >> 6] = s; lq[threadIdx.x >> 6] = sq; }
    __syncthreads();
    s  = ls[0] + ls[1] + ls[2] + ls[3];
    sq = lq[0] + lq[1] + lq[2] + lq[3];
    const float mu   = s * (1.0f / kDM);
    const float rstd = rsqrtf(sq * (1.0f / kDM) - mu * mu + 1e-5f);
    unsigned short* xo = Xn + (size_t)row * kDM;
    {
        const float4 gg = ((const float4*)g)[threadIdx.x];
        const float4 bb = ((const float4*)b)[threadIdx.x];
        ushort4 o;
        o.x = f2bf((v0.x - mu) * rstd * gg.x + bb.x);
        o.y = f2bf((v0.y - mu) * rstd * gg.y + bb.y);
        o.z = f2bf((v0.z - mu) * rstd * gg.z + bb.z);
        o.w = f2bf((v0.w - mu) * rstd * gg.w + bb.w);
        ((ushort4*)xo)[threadIdx.x] = o;
    }
    {
        const float4 gg = ((const float4*)g)[threadIdx.x + 256];
        const float4 bb = ((const float4*)b)[threadIdx.x + 256];
        ushort4 o;
        o.x = f2bf((v1.x - mu) * rstd * gg.x + bb.x);
        o.y = f2bf((v1.y - mu) * rstd * gg.y + bb.y);
        o.z = f2bf((v1.z - mu) * rstd * gg.z + bb.z);
        o.w = f2bf((v1.w - mu) * rstd * gg.w + bb.w);
        ((ushort4*)xo)[threadIdx.x + 256] = o;
    }
}

// ------------- weight transpose+cast: W[K][N] f32 -> Wt[N][K] bf16 -------------
// 64x64 tiles; float4 global reads, odd-stride(65) LDS, 16B coalesced stores.
__global__ __launch_bounds__(256) void wt_kernel(
        const float* __restrict__ W0, const float* __restrict__ W1,
        const float* __restrict__ W2, const float* __restrict__ W3,
        unsigned short* __restrict__ T0, unsigned short* __restrict__ T1,
        unsigned short* __restrict__ T2, unsigned short* __restrict__ T3) {
    const float* W; unsigned short* T;
    switch (blockIdx.z) {
        case 0:  W = W0; T = T0; break;
        case 1:  W = W1; T = T1; break;
        case 2:  W = W2; T = T2; break;
        default: W = W3; T = T3; break;
    }
    __shared__ float tile[64][65];
    const int t = threadIdx.x;
    const int r0 = blockIdx.y * 64, c0 = blockIdx.x * 64;
    const int lr = t >> 4, lc = (t & 15) * 4;
    #pragma unroll
    for (int i = 0; i < 4; ++i) {
        const float4 v = *(const float4*)&W[(size_t)(r0 + lr + i * 16) * kDM + c0 + lc];
        float* tp = &tile[lr + i * 16][lc];
        tp[0] = v.x; tp[1] = v.y; tp[2] = v.z; tp[3] = v.w;
    }
    __syncthreads();
    const int g = t & 7;
    #pragma unroll
    for (int j = 0; j < 2; ++j) {
        const int orr = (t >> 3) + j * 32;
        union { unsigned short u[8]; uint4 v; } o;
        #pragma unroll
        for (int jj = 0; jj < 8; ++jj)
            o.u[jj] = f2bf(tile[g * 8 + jj][orr]);
        *(uint4*)&T[(size_t)(c0 + orr) * kDM + r0 + g * 8] = o.v;
    }
}

// --- bias concat: [bq|bk|bv] -> 6144 floats ---
__global__ __launch_bounds__(256) void bias_pack(const float* __restrict__ bq,
        const float* __restrict__ bk, const float* __restrict__ bv,
        float* __restrict__ o) {
    const int i = blockIdx.x * 256 + threadIdx.x;
    o[i] = (i < 2048) ? bq[i] : ((i < 4096) ? bk[i - 2048] : bv[i - 4096]);
}

// --- V transpose: [bh][s][dh] bf16 -> [bh][dh][s] bf16, 64x64 tiles ---
__global__ __launch_bounds__(256) void vtr_kernel(const unsigned short* __restrict__ Vin,
                                                  unsigned short* __restrict__ Vout) {
    __shared__ __align__(16) unsigned short tile[64 * 72];
    const int bhz = blockIdx.z;
    const int s0 = blockIdx.x * 64, d0 = blockIdx.y * 64;
    const int t = threadIdx.x;
    const unsigned short* src = Vin + ((size_t)bhz * kS + s0) * kDH + d0;
    #pragma unroll
    for (int i = 0; i < 2; ++i) {
        const int r = (t >> 3) + 32 * i;
        const int g = t & 7;
        *(uint4*)(tile + r * 72 + g * 8) = *(const uint4*)(src + (size_t)r * kDH + g * 8);
    }
    __syncthreads();
    unsigned short* dst = Vout + ((size_t)bhz * kDH + d0) * kS + s0;
    #pragma unroll
    for (int i = 0; i < 2; ++i) {
        const int d = (t >> 3) + 32 * i;
        const int sg = t & 7;
        union { unsigned short u[8]; uint4 v; } o;
        #pragma unroll
        for (int j = 0; j < 8; ++j)
            o.u[j] = tile[(sg * 8 + j) * 72 + d];
        *(uint4*)(dst + (size_t)d * kS + sg * 8) = o.v;
    }
}

// ------------- GEMM (legacy 128x128, m97 structure): out-proj only -------------
__global__ __launch_bounds__(256) void gemm_kernel(
        const unsigned short* __restrict__ A, const unsigned short* __restrict__ Bt,
        const float* __restrict__ bias, void* __restrict__ C0, void* __restrict__ C1,
        void* __restrict__ C2, const float scale0, const int fp32out) {
    __shared__ __align__(16) unsigned short ldsA[2][128 * 32];
    __shared__ __align__(16) unsigned short ldsB[2][128 * 32];
    const int m0 = blockIdx.x * 128, n0 = blockIdx.y * 128;
    const int tid = threadIdx.x, lane = tid & 63, w = tid >> 6;
    const int wm = (w >> 1) * 64, wn = (w & 1) * 64;
    const int quad = lane >> 4, l15 = lane & 15;
    f32x4 acc[4][4] = {};
    const int srow = lane >> 2, scol = (lane & 3) * 8;
    for (int k0 = 0; k0 < kDM; k0 += 64) {
        __syncthreads();
        #pragma unroll
        for (int sub = 0; sub < 2; ++sub) {
            #pragma unroll
            for (int i = 0; i < 2; ++i) {
                const int c = w + i * 4;
                const int row = c * 16 + srow;
                const int kc = k0 + sub * 32 + scol;
                load_lds16(A  + (size_t)(m0 + row) * kDM + kc, &ldsA[sub][c * 512]);
                load_lds16(Bt + (size_t)(n0 + row) * kDM + kc, &ldsB[sub][c * 512]);
            }
        }
        __syncthreads();
        #pragma unroll
        for (int sub = 0; sub < 2; ++sub) {
            bf16x8 af[4], bfr[4];
            #pragma unroll
            for (int mt = 0; mt < 4; ++mt)
                af[mt] = *(const bf16x8*)(&ldsA[sub][(wm + mt * 16 + l15) * 32 + quad * 8]);
            #pragma unroll
            for (int nt = 0; nt < 4; ++nt)
                bfr[nt] = *(const bf16x8*)(&ldsB[sub][(wn + nt * 16 + l15) * 32 + quad * 8]);
            #pragma unroll
            for (int mt = 0; mt < 4; ++mt)
                #pragma unroll
                for (int nt = 0; nt < 4; ++nt)
                    acc[mt][nt] = __builtin_amdgcn_mfma_f32_16x16x32_bf16(af[mt], bfr[nt], acc[mt][nt], 0, 0, 0);
        }
    }
    const int proj = n0 >> 11;
    void* Cb = (proj == 0) ? C0 : ((proj == 1) ? C1 : C2);
    const float scl = (proj == 0) ? scale0 : 1.0f;
    #pragma unroll
    for (int mt = 0; mt < 4; ++mt) {
        #pragma unroll
        for (int nt = 0; nt < 4; ++nt) {
            const int ng = n0 + wn + nt * 16 + l15;
            const float bv = bias[ng];
            const int col = ng & 2047;
            const int h = col >> 7, dh = col & 127;
            #pragma unroll
            for (int r = 0; r < 4; ++r) {
                const int mg = m0 + wm + mt * 16 + quad * 4 + r;
                const float val = (acc[mt][nt][r] + bv) * scl;
                if (fp32out) {
                    ((float*)Cb)[(size_t)mg * kDM + ng] = val;
                } else {
                    const int bb = mg >> 11, ss = mg & 2047;
                    ((unsigned short*)Cb)[((size_t)(bb * kNH + h) * kS + ss) * kDH + dh] = f2bf(val);
                }
            }
        }
    }
}

// ------------- GEMM 256x128, 8-wave, BK=64, 2-phase counted-vmcnt pipeline -----
// R9/R10: tile 256x256 -> 256x128. Grid 16x48 = 768 = 3x256 CUs exactly: kills
// the 1.5-round tail (measured 75% util ceiling, Occ 16%) that capped R2-R8 at
// 123us. acc[8][2] = 64 VGPR (half of before; R6 spill impossible). LDS 96KB
// (sA 64 + sB 32), 1 block/CU, 8 waves. Per-phase MFMA density unchanged (16).
// Stage units/tile: B(ph1), A0(ph1), A1(ph2), all -> nxt (regions' last reads
// are >=2 barriers older). Waits: ph1-end vmcnt(4) certifies A1^t (issued t-1
// ph2, full-phase cover); boundary vmcnt(2) leaves A1^{t+1} in flight; last
// tile vmcnt(0) (vmcnt(4) would be a no-op there -- edge case handled).
__global__ __launch_bounds__(512, 2) void gemm256_kernel(
        const unsigned short* __restrict__ A, const unsigned short* __restrict__ Bt,
        const float* __restrict__ bias, void* __restrict__ C0, void* __restrict__ C1,
        void* __restrict__ C2, const float scale0) {
    __shared__ __align__(16) unsigned short sA[2][2 * 128 * 64];   // 64KB
    __shared__ __align__(16) unsigned short sB[2][128 * 64];       // 32KB
    const int tid = threadIdx.x, lane = tid & 63, w = tid >> 6;
    const int quad = lane >> 4, l15 = lane & 15;
    const int wr = w >> 2, wc = w & 3;          // 2M x 4N wave grid
    const int m0 = blockIdx.x * 256, n0 = blockIdx.y * 128;
    const int srow = lane >> 3;
    const int scol = ((lane & 7) ^ srow) * 8;   // inverse-swizzled global source
    size_t aOff[2], bOff[2]; int lOff[2];
    #pragma unroll
    for (int i = 0; i < 2; ++i) {
        const int wrow = (i * 8 + w) * 8 + srow;     // row within a 128-row half
        aOff[i] = (size_t)(m0 + wrow) * kDM + scol;  // + h*128*kDM + kt*64
        bOff[i] = (size_t)(n0 + wrow) * kDM + scol;
        lOff[i] = (i * 8 + w) * 512;                 // + h*8192 (A only)
    }
    const int swz = l15 & 7;
    int colq[2];
    #pragma unroll
    for (int ks = 0; ks < 2; ++ks) colq[ks] = ((ks * 4 + quad) ^ swz) * 8;

#define STG_A(buf, h, kt) { \
    load_lds16(A  + aOff[0] + (size_t)(h) * (128 * kDM) + (kt) * 64, &sA[buf][(h) * 8192 + lOff[0]]); \
    load_lds16(A  + aOff[1] + (size_t)(h) * (128 * kDM) + (kt) * 64, &sA[buf][(h) * 8192 + lOff[1]]); }
#define STG_B(buf, kt) { \
    load_lds16(Bt + bOff[0] + (size_t)(kt) * 64, &sB[buf][lOff[0]]); \
    load_lds16(Bt + bOff[1] + (size_t)(kt) * 64, &sB[buf][lOff[1]]); }

    f32x4 acc[8][2] = {};
    // prologue: tile 0 (B, A0, A1); wait B+A0, keep A1 in flight
    STG_B(0, 0); STG_A(0, 0, 0); STG_A(0, 1, 0);
    asm volatile("s_waitcnt vmcnt(2)" ::: "memory");
    __builtin_amdgcn_s_barrier();

    const int NT = kDM / 64;                    // 32 K-tiles
    bf16x8 af[4][2], bfr[2][2];
    for (int t = 0; t < NT; ++t) {
        const int cur = t & 1, nxt = cur ^ 1;
        // ---- phase 1: read A-lo + B; stage B^{t+1}, A0^{t+1}; mfma (m-lo)
        #pragma unroll
        for (int mt = 0; mt < 4; ++mt)
            #pragma unroll
            for (int ks = 0; ks < 2; ++ks)
                af[mt][ks] = *(const bf16x8*)(&sA[cur][(wr * 128 + mt * 16 + l15) * 64 + colq[ks]]);
        #pragma unroll
        for (int nt = 0; nt < 2; ++nt)
            #pragma unroll
            for (int ks = 0; ks < 2; ++ks)
                bfr[nt][ks] = *(const bf16x8*)(&sB[cur][(wc * 32 + nt * 16 + l15) * 64 + colq[ks]]);
        if (t + 1 < NT) { STG_B(nxt, t + 1); STG_A(nxt, 0, t + 1); }
        __builtin_amdgcn_s_barrier();
        asm volatile("s_waitcnt lgkmcnt(0)" ::: "memory");
        __builtin_amdgcn_s_setprio(1);
        #pragma unroll
        for (int mt = 0; mt < 4; ++mt)
            #pragma unroll
            for (int nt = 0; nt < 2; ++nt)
                #pragma unroll
                for (int ks = 0; ks < 2; ++ks)
                    acc[mt][nt] = __builtin_amdgcn_mfma_f32_16x16x32_bf16(af[mt][ks], bfr[nt][ks], acc[mt][nt], 0, 0, 0);
        __builtin_amdgcn_s_setprio(0);
        if (t + 1 < NT) { asm volatile("s_waitcnt vmcnt(4)" ::: "memory"); }
        else            { asm volatile("s_waitcnt vmcnt(0)" ::: "memory"); }
        __builtin_amdgcn_s_barrier();           // A1^t certified resident (all waves)
        // ---- phase 2: read A-hi; stage A1^{t+1}; mfma (m-hi)
        #pragma unroll
        for (int mt = 0; mt < 4; ++mt)
            #pragma unroll
            for (int ks = 0; ks < 2; ++ks)
                af[mt][ks] = *(const bf16x8*)(&sA[cur][(wr * 128 + 64 + mt * 16 + l15) * 64 + colq[ks]]);
        if (t + 1 < NT) STG_A(nxt, 1, t + 1);
        __builtin_amdgcn_s_barrier();
        asm volatile("s_waitcnt lgkmcnt(0)" ::: "memory");
        __builtin_amdgcn_s_setprio(1);
        #pragma unroll
        for (int mt = 0; mt < 4; ++mt)
            #pragma unroll
            for (int nt = 0; nt < 2; ++nt)
                #pragma unroll
                for (int ks = 0; ks < 2; ++ks)
                    acc[4 + mt][nt] = __builtin_amdgcn_mfma_f32_16x16x32_bf16(af[mt][ks], bfr[nt][ks], acc[4 + mt][nt], 0, 0, 0);
        __builtin_amdgcn_s_setprio(0);
        if (t + 1 < NT) {
            asm volatile("s_waitcnt vmcnt(2)" ::: "memory");  // B+A0^{t+1} landed; A1^{t+1} flies
            __builtin_amdgcn_s_barrier();
        }
    }
#undef STG_A
#undef STG_B
    // epilogue: bf16 scatter to [B,H,S,Dh]; scale on proj 0 (Q)
    const int proj = n0 >> 11;
    void* Cb = (proj == 0) ? C0 : ((proj == 1) ? C1 : C2);
    const float scl = (proj == 0) ? scale0 : 1.0f;
    #pragma unroll
    for (int mt = 0; mt < 8; ++mt) {
        #pragma unroll
        for (int nt = 0; nt < 2; ++nt) {
            const int ng = n0 + wc * 32 + nt * 16 + l15;
            const float bv = bias[ng];
            const int col = ng & 2047;
            const int h = col >> 7, dh = col & 127;
            #pragma unroll
            for (int r = 0; r < 4; ++r) {
                const int mg = m0 + wr * 128 + mt * 16 + quad * 4 + r;
                const float val = (acc[mt][nt][r] + bv) * scl;
                const int bb = mg >> 11, ss = mg & 2047;
                ((unsigned short*)Cb)[((size_t)(bb * kNH + h) * kS + ss) * kDH + dh] = f2bf(val);
            }
        }
    }
}

// ------------- causal flash attention, S^T form, paired q-tiles -------------
// R9/R10: R4 structure (256 thr, dbuf K/V, T13 defer-max, T5 setprio).
// R7's dual-q-tile halved K/V traffic with ZERO time change -> K/V is L2/L3-
// resident (32MB total); attn is not HBM-bound. Do not re-try traffic cuts.
__global__ __launch_bounds__(256, 2) void attn_kernel(
        const unsigned short* __restrict__ Q, const unsigned short* __restrict__ Kk,
        const unsigned short* __restrict__ Vt, unsigned short* __restrict__ AV) {
    __shared__ __align__(16) unsigned short ldsK[2][64 * 128];   // swizzled [key][d]
    __shared__ __align__(16) unsigned short ldsV[2][128 * 64];   // swizzled [d][key]
    __shared__ __align__(16) unsigned short ldsP[4 * 16 * 64];   // per-wave swizzled [q][key]
    const int bh = blockIdx.x, pr = blockIdx.y;
    const unsigned short* Qb = Q  + (size_t)bh * kS * kDH;
    const unsigned short* Kb = Kk + (size_t)bh * kS * kDH;
    const unsigned short* Vb = Vt + (size_t)bh * kDH * kS;
    const int tid = threadIdx.x, lane = tid & 63, w = tid >> 6;
    const int quad = lane >> 4, l15 = lane & 15;
    int kSrc[4], vSrc[4], ldst[4];
    #pragma unroll
    for (int i = 0; i < 4; ++i) {
        const int c = w * 4 + i;
        const int rK = c * 4 + (lane >> 4);
        const int gK = (lane & 15) ^ (rK & 15);
        kSrc[i] = rK * kDH + gK * 8;
        const int dV = c * 8 + (lane >> 3);
        const int gV = (lane & 7) ^ (dV & 7);
        vSrc[i] = dV * kS + gV * 8;
        ldst[i] = c * 512;
    }
    unsigned short* pw = ldsP + w * 1024;
    const int pswz = 2 * (l15 & 7);
    const int bb = bh >> 4, h = bh & 15;
    for (int half = 0; half < 2; ++half) {
        const int qt = half ? (31 - pr) : pr;
        const int qrow0 = qt * 64 + w * 16;
        bf16x8 qf[4];
        #pragma unroll
        for (int kk = 0; kk < 4; ++kk)
            qf[kk] = *(const bf16x8*)(Qb + (size_t)(qrow0 + l15) * kDH + kk * 32 + quad * 8);
        f32x4 accO[8] = {};
        float mrun = -3.0e38f, lrun = 0.0f;
        #pragma unroll
        for (int i = 0; i < 4; ++i) {
            load_lds16(Kb + kSrc[i], &ldsK[0][ldst[i]]);
            load_lds16(Vb + vSrc[i], &ldsV[0][ldst[i]]);
        }
        __syncthreads();
        int cur = 0;
        for (int kt = 0; kt <= qt; ++kt) {
            if (kt < qt) {
                #pragma unroll
                for (int i = 0; i < 4; ++i) {
                    load_lds16(Kb + (size_t)(kt + 1) * (64 * kDH) + kSrc[i], &ldsK[cur ^ 1][ldst[i]]);
                    load_lds16(Vb + (kt + 1) * 64 + vSrc[i], &ldsV[cur ^ 1][ldst[i]]);
                }
            }
            f32x4 accS[4] = {};
            __builtin_amdgcn_s_setprio(1);
            #pragma unroll
            for (int kk = 0; kk < 4; ++kk) {
                bf16x8 kf[4];
                #pragma unroll
                for (int mt = 0; mt < 4; ++mt)
                    kf[mt] = *(const bf16x8*)(&ldsK[cur][(mt * 16 + l15) * 128 + (((kk * 4 + quad) ^ l15) << 3)]);
                #pragma unroll
                for (int mt = 0; mt < 4; ++mt)
                    accS[mt] = __builtin_amdgcn_mfma_f32_16x16x32_bf16(kf[mt], qf[kk], accS[mt], 0, 0, 0);
            }
            __builtin_amdgcn_s_setprio(0);
            if (kt == qt) {
                const int ql = w * 16 + l15;
                #pragma unroll
                for (int mt = 0; mt < 4; ++mt)
                    #pragma unroll
                    for (int r = 0; r < 4; ++r)
                        if (mt * 16 + quad * 4 + r > ql) accS[mt][r] = -3.0e38f;
            }
            float mx = accS[0][0];
            #pragma unroll
            for (int mt = 0; mt < 4; ++mt)
                #pragma unroll
                for (int r = 0; r < 4; ++r) mx = fmaxf(mx, accS[mt][r]);
            mx = fmaxf(mx, __shfl_xor(mx, 16));
            mx = fmaxf(mx, __shfl_xor(mx, 32));
            if (!__all(mx - mrun <= 8.0f)) {    // T13 defer-max
                const float mnew = fmaxf(mrun, mx);
                const float al = fast_exp2(mrun - mnew);
                lrun *= al;
                float albr[4];
                #pragma unroll
                for (int r = 0; r < 4; ++r)
                    albr[r] = __shfl(al, (lane & 48) | (quad << 2) | r);
                #pragma unroll
                for (int dt = 0; dt < 8; ++dt)
                    #pragma unroll
                    for (int r = 0; r < 4; ++r)
                        accO[dt][r] *= albr[r];
                mrun = mnew;
            }
            float rs = 0.f;
            #pragma unroll
            for (int mt = 0; mt < 4; ++mt) {
                ushort4 pk;
                unsigned short* pe = (unsigned short*)&pk;
                #pragma unroll
                for (int r = 0; r < 4; ++r) {
                    const float p = fast_exp2(accS[mt][r] - mrun);
                    const unsigned short pb = f2bf(p);
                    pe[r] = pb;
                    rs += bf2f(pb);
                }
                *(ushort4*)(pw + l15 * 64 + (((mt * 4 + quad) ^ pswz) << 2)) = pk;
            }
            rs += __shfl_xor(rs, 16);
            rs += __shfl_xor(rs, 32);
            lrun += rs;
            asm volatile("s_waitcnt lgkmcnt(0)" ::: "memory");
            __builtin_amdgcn_s_setprio(1);
            #pragma unroll
            for (int kk = 0; kk < 2; ++kk) {
                const bf16x8 pa = *(const bf16x8*)(pw + l15 * 64 + (((kk * 8 + quad * 2) ^ pswz) << 2));
                #pragma unroll
                for (int dt = 0; dt < 8; ++dt) {
                    const bf16x8 vf = *(const bf16x8*)(&ldsV[cur][(dt * 16 + l15) * 64 + (((kk * 4 + quad) ^ (l15 & 7)) << 3)]);
                    accO[dt] = __builtin_amdgcn_mfma_f32_16x16x32_bf16(pa, vf, accO[dt], 0, 0, 0);
                }
            }
            __builtin_amdgcn_s_setprio(0);
            __syncthreads();
            cur ^= 1;
        }
        float linv[4];
        #pragma unroll
        for (int r = 0; r < 4; ++r)
            linv[r] = __shfl(lrun, (lane & 48) | (quad << 2) | r);
        #pragma unroll
        for (int r = 0; r < 4; ++r) {
            const float inv = 1.0f / linv[r];
            unsigned short* orow = AV + ((size_t)bb * kS + qrow0 + quad * 4 + r) * kDM + h * kDH;
            #pragma unroll
            for (int dt = 0; dt < 8; ++dt)
                orow[dt * 16 + l15] = f2bf(accO[dt][r] * inv);
        }
    }
}

extern "C" void kernel_launch(void* const* d_in, const int* in_sizes, int n_in,
                              void* d_out, int out_size, void* d_ws, size_t ws_size,
                              hipStream_t stream) {
    const float* X   = (const float*)d_in[0];
    const float* lng = (const float*)d_in[1];
    const float* lnb = (const float*)d_in[2];
    const float* Wq  = (const float*)d_in[3];
    const float* bq  = (const float*)d_in[4];
    const float* Wk  = (const float*)d_in[5];
    const float* bk  = (const float*)d_in[6];
    const float* Wv  = (const float*)d_in[7];
    const float* bv  = (const float*)d_in[8];
    const float* Wo  = (const float*)d_in[9];
    const float* bo  = (const float*)d_in[10];
    float* out = (float*)d_out;

    char* p = (char*)d_ws;
    unsigned short* Xn  = (unsigned short*)p; p += (size_t)kM * kDM * 2;
    unsigned short* Wqt = (unsigned short*)p; p += (size_t)kDM * kDM * 2;  // Wq|Wk|Wv contiguous
    unsigned short* Wkt = (unsigned short*)p; p += (size_t)kDM * kDM * 2;
    unsigned short* Wvt = (unsigned short*)p; p += (size_t)kDM * kDM * 2;
    unsigned short* Wot = (unsigned short*)p; p += (size_t)kDM * kDM * 2;
    unsigned short* Qb  = (unsigned short*)p; p += (size_t)kM * kDM * 2;
    unsigned short* Kb  = (unsigned short*)p; p += (size_t)kM * kDM * 2;
    unsigned short* Vtb = (unsigned short*)p; p += (size_t)kM * kDM * 2;
    unsigned short* AV  = (unsigned short*)p; p += (size_t)kM * kDM * 2;
    unsigned short* Vtmp = AV;        // alias: consumed by vtr before attn writes AV
    float* biasc = (float*)Vtb;       // alias: consumed by qkv-gemm before vtr writes Vtb

    const float qscale = 0.08838834764831845f * 1.4426950408889634f;

    ln_kernel<<<dim3(kM), dim3(256), 0, stream>>>(X, lng, lnb, Xn);
    wt_kernel<<<dim3(32, 32, 4), dim3(256), 0, stream>>>(Wq, Wk, Wv, Wo, Wqt, Wkt, Wvt, Wot);
    bias_pack<<<dim3(24), dim3(256), 0, stream>>>(bq, bk, bv, biasc);
    // fused QKV GEMM: 256x128 tiles, grid 16x48 = 768 = 3 full CU rounds
    gemm256_kernel<<<dim3(16, 48), dim3(512), 0, stream>>>(Xn, Wqt, biasc, Qb, Kb, Vtmp, qscale);
    vtr_kernel<<<dim3(32, 2, 32), dim3(256), 0, stream>>>(Vtmp, Vtb);
    attn_kernel<<<dim3(32, 16), dim3(256), 0, stream>>>(Qb, Kb, Vtb, AV);
    gemm_kernel<<<dim3(32, 16), dim3(256), 0, stream>>>(AV, Wot, bo, out, out, out, 1.0f, 1);
}

// Round 14
// 362.252 us; speedup vs baseline: 2.5100x; 1.0516x over previous
//
#include <hip/hip_runtime.h>
#include <cstdint>

constexpr int kDM = 2048;   // d_model
constexpr int kNH = 16;     // heads
constexpr int kDH = 128;    // head dim
constexpr int kS  = 2048;   // seq
constexpr int kM  = 4096;   // B*S rows

typedef __bf16 bf16x8 __attribute__((ext_vector_type(8)));
typedef float  f32x4  __attribute__((ext_vector_type(4)));

__device__ __forceinline__ unsigned short f2bf(float f) {
    union { float f; unsigned u; } v; v.f = f;
    unsigned u = v.u;
    u += 0x7fffu + ((u >> 16) & 1u);   // RNE
    return (unsigned short)(u >> 16);
}
__device__ __forceinline__ float bf2f(unsigned short b) {
    union { unsigned u; float f; } v; v.u = ((unsigned)b) << 16;
    return v.f;
}
__device__ __forceinline__ float fast_exp2(float x) {
#if __has_builtin(__builtin_amdgcn_exp2f)
    return __builtin_amdgcn_exp2f(x);
#else
    return exp2f(x);
#endif
}
// async global->LDS, 16B per lane, LDS dest = wave-uniform base + lane*16
__device__ __forceinline__ void load_lds16(const void* g, void* l) {
    auto gp = (__attribute__((address_space(1))) unsigned int*)(uintptr_t)g;
    auto lp = (__attribute__((address_space(3))) unsigned int*)(uintptr_t)l;
    __builtin_amdgcn_global_load_lds(gp, lp, 16, 0, 0);
}

// ---------------- LayerNorm: fp32 in -> bf16 out ----------------
__global__ __launch_bounds__(256) void ln_kernel(const float* __restrict__ X,
        const float* __restrict__ g, const float* __restrict__ b,
        unsigned short* __restrict__ Xn) {
    const int row = blockIdx.x;
    const float* xr = X + (size_t)row * kDM;
    const float4 v0 = ((const float4*)xr)[threadIdx.x];
    const float4 v1 = ((const float4*)xr)[threadIdx.x + 256];
    float s  = v0.x + v0.y + v0.z + v0.w + v1.x + v1.y + v1.z + v1.w;
    float sq = v0.x*v0.x + v0.y*v0.y + v0.z*v0.z + v0.w*v0.w
             + v1.x*v1.x + v1.y*v1.y + v1.z*v1.z + v1.w*v1.w;
    #pragma unroll
    for (int m = 1; m < 64; m <<= 1) { s += __shfl_xor(s, m); sq += __shfl_xor(sq, m); }
    __shared__ float ls[4], lq[4];
    if ((threadIdx.x & 63) == 0) { ls[threadIdx.x >> 6] = s; lq[threadIdx.x >> 6] = sq; }
    __syncthreads();
    s  = ls[0] + ls[1] + ls[2] + ls[3];
    sq = lq[0] + lq[1] + lq[2] + lq[3];
    const float mu   = s * (1.0f / kDM);
    const float rstd = rsqrtf(sq * (1.0f / kDM) - mu * mu + 1e-5f);
    unsigned short* xo = Xn + (size_t)row * kDM;
    {
        const float4 gg = ((const float4*)g)[threadIdx.x];
        const float4 bb = ((const float4*)b)[threadIdx.x];
        ushort4 o;
        o.x = f2bf((v0.x - mu) * rstd * gg.x + bb.x);
        o.y = f2bf((v0.y - mu) * rstd * gg.y + bb.y);
        o.z = f2bf((v0.z - mu) * rstd * gg.z + bb.z);
        o.w = f2bf((v0.w - mu) * rstd * gg.w + bb.w);
        ((ushort4*)xo)[threadIdx.x] = o;
    }
    {
        const float4 gg = ((const float4*)g)[threadIdx.x + 256];
        const float4 bb = ((const float4*)b)[threadIdx.x + 256];
        ushort4 o;
        o.x = f2bf((v1.x - mu) * rstd * gg.x + bb.x);
        o.y = f2bf((v1.y - mu) * rstd * gg.y + bb.y);
        o.z = f2bf((v1.z - mu) * rstd * gg.z + bb.z);
        o.w = f2bf((v1.w - mu) * rstd * gg.w + bb.w);
        ((ushort4*)xo)[threadIdx.x + 256] = o;
    }
}

// ------------- weight transpose+cast: W[K][N] f32 -> Wt[N][K] bf16 -------------
// 64x64 tiles; float4 global reads, odd-stride(65) LDS, 16B coalesced stores.
__global__ __launch_bounds__(256) void wt_kernel(
        const float* __restrict__ W0, const float* __restrict__ W1,
        const float* __restrict__ W2, const float* __restrict__ W3,
        unsigned short* __restrict__ T0, unsigned short* __restrict__ T1,
        unsigned short* __restrict__ T2, unsigned short* __restrict__ T3) {
    const float* W; unsigned short* T;
    switch (blockIdx.z) {
        case 0:  W = W0; T = T0; break;
        case 1:  W = W1; T = T1; break;
        case 2:  W = W2; T = T2; break;
        default: W = W3; T = T3; break;
    }
    __shared__ float tile[64][65];
    const int t = threadIdx.x;
    const int r0 = blockIdx.y * 64, c0 = blockIdx.x * 64;
    const int lr = t >> 4, lc = (t & 15) * 4;
    #pragma unroll
    for (int i = 0; i < 4; ++i) {
        const float4 v = *(const float4*)&W[(size_t)(r0 + lr + i * 16) * kDM + c0 + lc];
        float* tp = &tile[lr + i * 16][lc];
        tp[0] = v.x; tp[1] = v.y; tp[2] = v.z; tp[3] = v.w;
    }
    __syncthreads();
    const int g = t & 7;
    #pragma unroll
    for (int j = 0; j < 2; ++j) {
        const int orr = (t >> 3) + j * 32;
        union { unsigned short u[8]; uint4 v; } o;
        #pragma unroll
        for (int jj = 0; jj < 8; ++jj)
            o.u[jj] = f2bf(tile[g * 8 + jj][orr]);
        *(uint4*)&T[(size_t)(c0 + orr) * kDM + r0 + g * 8] = o.v;
    }
}

// --- bias concat: [bq|bk|bv] -> 6144 floats ---
__global__ __launch_bounds__(256) void bias_pack(const float* __restrict__ bq,
        const float* __restrict__ bk, const float* __restrict__ bv,
        float* __restrict__ o) {
    const int i = blockIdx.x * 256 + threadIdx.x;
    o[i] = (i < 2048) ? bq[i] : ((i < 4096) ? bk[i - 2048] : bv[i - 4096]);
}

// ------------- GEMM 256x128, 8-wave, BK=64, 2-phase counted-vmcnt pipeline -----
// R12 RACE FIX: R9-R11 had ph1 waves wr=1 reading LDS rows 128-191 (the A1
// half) while only {B,A0} were vmcnt-certified -> timing-dependent corruption
// (R11: absmax 0.0106 -> 0.0273 under replay). Fix: remap per-wave rows so ph1
// reads ONLY A0 for both wr (rows wr*64+mt*16 in [0,128)) and ph2 reads ONLY
// A1 (rows 128+wr*64+mt*16). Wait invariants now hold exactly: boundary
// vmcnt(2) certifies {B,A0} (ph1's working set); mid-tile vmcnt(4) drains A1^t
// before ph2 reads it; last tile vmcnt(0). Epilogue mg remapped to match.
// Epilogues: proj==2 writes V transposed [bh][dh][s] (vtr eliminated);
// fp32out path serves the out-proj (grid 16x16 = 1 exact CU round).
__global__ __launch_bounds__(512, 2) void gemm256_kernel(
        const unsigned short* __restrict__ A, const unsigned short* __restrict__ Bt,
        const float* __restrict__ bias, void* __restrict__ C0, void* __restrict__ C1,
        void* __restrict__ C2, const float scale0, const int fp32out) {
    __shared__ __align__(16) unsigned short sA[2][2 * 128 * 64];   // 64KB
    __shared__ __align__(16) unsigned short sB[2][128 * 64];       // 32KB
    const int tid = threadIdx.x, lane = tid & 63, w = tid >> 6;
    const int quad = lane >> 4, l15 = lane & 15;
    const int wr = w >> 2, wc = w & 3;          // 2M x 4N wave grid
    const int m0 = blockIdx.x * 256, n0 = blockIdx.y * 128;
    const int srow = lane >> 3;
    const int scol = ((lane & 7) ^ srow) * 8;   // inverse-swizzled global source
    size_t aOff[2], bOff[2]; int lOff[2];
    #pragma unroll
    for (int i = 0; i < 2; ++i) {
        const int wrow = (i * 8 + w) * 8 + srow;     // row within a 128-row half
        aOff[i] = (size_t)(m0 + wrow) * kDM + scol;  // + h*128*kDM + kt*64
        bOff[i] = (size_t)(n0 + wrow) * kDM + scol;
        lOff[i] = (i * 8 + w) * 512;                 // + h*8192 (A only)
    }
    const int swz = l15 & 7;
    int colq[2];
    #pragma unroll
    for (int ks = 0; ks < 2; ++ks) colq[ks] = ((ks * 4 + quad) ^ swz) * 8;

#define STG_A(buf, h, kt) { \
    load_lds16(A  + aOff[0] + (size_t)(h) * (128 * kDM) + (kt) * 64, &sA[buf][(h) * 8192 + lOff[0]]); \
    load_lds16(A  + aOff[1] + (size_t)(h) * (128 * kDM) + (kt) * 64, &sA[buf][(h) * 8192 + lOff[1]]); }
#define STG_B(buf, kt) { \
    load_lds16(Bt + bOff[0] + (size_t)(kt) * 64, &sB[buf][lOff[0]]); \
    load_lds16(Bt + bOff[1] + (size_t)(kt) * 64, &sB[buf][lOff[1]]); }

    f32x4 acc[8][2] = {};
    // prologue: tile 0 (B, A0, A1); wait B+A0, keep A1 in flight
    STG_B(0, 0); STG_A(0, 0, 0); STG_A(0, 1, 0);
    asm volatile("s_waitcnt vmcnt(2)" ::: "memory");
    __builtin_amdgcn_s_barrier();

    const int NT = kDM / 64;                    // 32 K-tiles
    bf16x8 af[4][2], bfr[2][2];
    for (int t = 0; t < NT; ++t) {
        const int cur = t & 1, nxt = cur ^ 1;
        // ---- phase 1: read A0 rows (wr*64..wr*64+63) + B; stage B^{t+1}, A0^{t+1}
        #pragma unroll
        for (int mt = 0; mt < 4; ++mt)
            #pragma unroll
            for (int ks = 0; ks < 2; ++ks)
                af[mt][ks] = *(const bf16x8*)(&sA[cur][(wr * 64 + mt * 16 + l15) * 64 + colq[ks]]);
        #pragma unroll
        for (int nt = 0; nt < 2; ++nt)
            #pragma unroll
            for (int ks = 0; ks < 2; ++ks)
                bfr[nt][ks] = *(const bf16x8*)(&sB[cur][(wc * 32 + nt * 16 + l15) * 64 + colq[ks]]);
        if (t + 1 < NT) { STG_B(nxt, t + 1); STG_A(nxt, 0, t + 1); }
        __builtin_amdgcn_s_barrier();
        asm volatile("s_waitcnt lgkmcnt(0)" ::: "memory");
        __builtin_amdgcn_s_setprio(1);
        #pragma unroll
        for (int mt = 0; mt < 4; ++mt)
            #pragma unroll
            for (int nt = 0; nt < 2; ++nt)
                #pragma unroll
                for (int ks = 0; ks < 2; ++ks)
                    acc[mt][nt] = __builtin_amdgcn_mfma_f32_16x16x32_bf16(af[mt][ks], bfr[nt][ks], acc[mt][nt], 0, 0, 0);
        __builtin_amdgcn_s_setprio(0);
        if (t + 1 < NT) { asm volatile("s_waitcnt vmcnt(4)" ::: "memory"); }
        else            { asm volatile("s_waitcnt vmcnt(0)" ::: "memory"); }
        __builtin_amdgcn_s_barrier();           // A1^t certified resident (all waves)
        // ---- phase 2: read A1 rows (128+wr*64..); stage A1^{t+1}
        #pragma unroll
        for (int mt = 0; mt < 4; ++mt)
            #pragma unroll
            for (int ks = 0; ks < 2; ++ks)
                af[mt][ks] = *(const bf16x8*)(&sA[cur][(128 + wr * 64 + mt * 16 + l15) * 64 + colq[ks]]);
        if (t + 1 < NT) STG_A(nxt, 1, t + 1);
        __builtin_amdgcn_s_barrier();
        asm volatile("s_waitcnt lgkmcnt(0)" ::: "memory");
        __builtin_amdgcn_s_setprio(1);
        #pragma unroll
        for (int mt = 0; mt < 4; ++mt)
            #pragma unroll
            for (int nt = 0; nt < 2; ++nt)
                #pragma unroll
                for (int ks = 0; ks < 2; ++ks)
                    acc[4 + mt][nt] = __builtin_amdgcn_mfma_f32_16x16x32_bf16(af[mt][ks], bfr[nt][ks], acc[4 + mt][nt], 0, 0, 0);
        __builtin_amdgcn_s_setprio(0);
        if (t + 1 < NT) {
            asm volatile("s_waitcnt vmcnt(2)" ::: "memory");  // B+A0^{t+1} landed; A1^{t+1} flies
            __builtin_amdgcn_s_barrier();
        }
    }
#undef STG_A
#undef STG_B
    // ---- epilogue ----  (mrow matches the race-fixed read mapping)
    const int proj = n0 >> 11;
    if (fp32out) {
        float* Cb = (float*)C0;
        #pragma unroll
        for (int mt = 0; mt < 8; ++mt) {
            const int mrow = (mt & 4) * 32 + wr * 64 + (mt & 3) * 16;
            #pragma unroll
            for (int nt = 0; nt < 2; ++nt) {
                const int ng = n0 + wc * 32 + nt * 16 + l15;
                const float bv = bias[ng];
                #pragma unroll
                for (int r = 0; r < 4; ++r) {
                    const int mg = m0 + mrow + quad * 4 + r;
                    Cb[(size_t)mg * kDM + ng] = acc[mt][nt][r] + bv;
                }
            }
        }
    } else if (proj == 2) {
        // V: write transposed [bh][dh][s]; 4 consecutive s pack into ushort4
        unsigned short* Cb = (unsigned short*)C2;
        #pragma unroll
        for (int mt = 0; mt < 8; ++mt) {
            const int mrow = (mt & 4) * 32 + wr * 64 + (mt & 3) * 16;
            const int mgb = m0 + mrow + quad * 4;
            const int bb = mgb >> 11, ss = mgb & 2047;
            #pragma unroll
            for (int nt = 0; nt < 2; ++nt) {
                const int ng = n0 + wc * 32 + nt * 16 + l15;
                const float bv = bias[ng];
                const int col = ng & 2047;
                const int h = col >> 7, dh = col & 127;
                ushort4 o;
                o.x = f2bf(acc[mt][nt][0] + bv);
                o.y = f2bf(acc[mt][nt][1] + bv);
                o.z = f2bf(acc[mt][nt][2] + bv);
                o.w = f2bf(acc[mt][nt][3] + bv);
                *(ushort4*)&Cb[((size_t)(bb * kNH + h) * kDH + dh) * kS + ss] = o;
            }
        }
    } else {
        void* Cb = (proj == 0) ? C0 : C1;
        const float scl = (proj == 0) ? scale0 : 1.0f;
        #pragma unroll
        for (int mt = 0; mt < 8; ++mt) {
            const int mrow = (mt & 4) * 32 + wr * 64 + (mt & 3) * 16;
            #pragma unroll
            for (int nt = 0; nt < 2; ++nt) {
                const int ng = n0 + wc * 32 + nt * 16 + l15;
                const float bv = bias[ng];
                const int col = ng & 2047;
                const int h = col >> 7, dh = col & 127;
                #pragma unroll
                for (int r = 0; r < 4; ++r) {
                    const int mg = m0 + mrow + quad * 4 + r;
                    const float val = (acc[mt][nt][r] + bv) * scl;
                    const int bb = mg >> 11, ss = mg & 2047;
                    ((unsigned short*)Cb)[((size_t)(bb * kNH + h) * kS + ss) * kDH + dh] = f2bf(val);
                }
            }
        }
    }
}

// ------------- causal flash attention, S^T form, paired q-tiles -------------
// R4 structure (256 thr, dbuf K/V, T13 defer-max, T5 setprio). R7's dual-q-tile
// halved K/V traffic with ZERO time change -> K/V is L2/L3-resident; attn is
// not HBM-bound. Do not re-try traffic cuts.
__global__ __launch_bounds__(256, 2) void attn_kernel(
        const unsigned short* __restrict__ Q, const unsigned short* __restrict__ Kk,
        const unsigned short* __restrict__ Vt, unsigned short* __restrict__ AV) {
    __shared__ __align__(16) unsigned short ldsK[2][64 * 128];   // swizzled [key][d]
    __shared__ __align__(16) unsigned short ldsV[2][128 * 64];   // swizzled [d][key]
    __shared__ __align__(16) unsigned short ldsP[4 * 16 * 64];   // per-wave swizzled [q][key]
    const int bh = blockIdx.x, pr = blockIdx.y;
    const unsigned short* Qb = Q  + (size_t)bh * kS * kDH;
    const unsigned short* Kb = Kk + (size_t)bh * kS * kDH;
    const unsigned short* Vb = Vt + (size_t)bh * kDH * kS;
    const int tid = threadIdx.x, lane = tid & 63, w = tid >> 6;
    const int quad = lane >> 4, l15 = lane & 15;
    int kSrc[4], vSrc[4], ldst[4];
    #pragma unroll
    for (int i = 0; i < 4; ++i) {
        const int c = w * 4 + i;
        const int rK = c * 4 + (lane >> 4);
        const int gK = (lane & 15) ^ (rK & 15);
        kSrc[i] = rK * kDH + gK * 8;
        const int dV = c * 8 + (lane >> 3);
        const int gV = (lane & 7) ^ (dV & 7);
        vSrc[i] = dV * kS + gV * 8;
        ldst[i] = c * 512;
    }
    unsigned short* pw = ldsP + w * 1024;
    const int pswz = 2 * (l15 & 7);
    const int bb = bh >> 4, h = bh & 15;
    for (int half = 0; half < 2; ++half) {
        const int qt = half ? (31 - pr) : pr;
        const int qrow0 = qt * 64 + w * 16;
        bf16x8 qf[4];
        #pragma unroll
        for (int kk = 0; kk < 4; ++kk)
            qf[kk] = *(const bf16x8*)(Qb + (size_t)(qrow0 + l15) * kDH + kk * 32 + quad * 8);
        f32x4 accO[8] = {};
        float mrun = -3.0e38f, lrun = 0.0f;
        #pragma unroll
        for (int i = 0; i < 4; ++i) {
            load_lds16(Kb + kSrc[i], &ldsK[0][ldst[i]]);
            load_lds16(Vb + vSrc[i], &ldsV[0][ldst[i]]);
        }
        __syncthreads();
        int cur = 0;
        for (int kt = 0; kt <= qt; ++kt) {
            if (kt < qt) {
                #pragma unroll
                for (int i = 0; i < 4; ++i) {
                    load_lds16(Kb + (size_t)(kt + 1) * (64 * kDH) + kSrc[i], &ldsK[cur ^ 1][ldst[i]]);
                    load_lds16(Vb + (kt + 1) * 64 + vSrc[i], &ldsV[cur ^ 1][ldst[i]]);
                }
            }
            f32x4 accS[4] = {};
            __builtin_amdgcn_s_setprio(1);
            #pragma unroll
            for (int kk = 0; kk < 4; ++kk) {
                bf16x8 kf[4];
                #pragma unroll
                for (int mt = 0; mt < 4; ++mt)
                    kf[mt] = *(const bf16x8*)(&ldsK[cur][(mt * 16 + l15) * 128 + (((kk * 4 + quad) ^ l15) << 3)]);
                #pragma unroll
                for (int mt = 0; mt < 4; ++mt)
                    accS[mt] = __builtin_amdgcn_mfma_f32_16x16x32_bf16(kf[mt], qf[kk], accS[mt], 0, 0, 0);
            }
            __builtin_amdgcn_s_setprio(0);
            if (kt == qt) {
                const int ql = w * 16 + l15;
                #pragma unroll
                for (int mt = 0; mt < 4; ++mt)
                    #pragma unroll
                    for (int r = 0; r < 4; ++r)
                        if (mt * 16 + quad * 4 + r > ql) accS[mt][r] = -3.0e38f;
            }
            float mx = accS[0][0];
            #pragma unroll
            for (int mt = 0; mt < 4; ++mt)
                #pragma unroll
                for (int r = 0; r < 4; ++r) mx = fmaxf(mx, accS[mt][r]);
            mx = fmaxf(mx, __shfl_xor(mx, 16));
            mx = fmaxf(mx, __shfl_xor(mx, 32));
            if (!__all(mx - mrun <= 8.0f)) {    // T13 defer-max
                const float mnew = fmaxf(mrun, mx);
                const float al = fast_exp2(mrun - mnew);
                lrun *= al;
                float albr[4];
                #pragma unroll
                for (int r = 0; r < 4; ++r)
                    albr[r] = __shfl(al, (lane & 48) | (quad << 2) | r);
                #pragma unroll
                for (int dt = 0; dt < 8; ++dt)
                    #pragma unroll
                    for (int r = 0; r < 4; ++r)
                        accO[dt][r] *= albr[r];
                mrun = mnew;
            }
            float rs = 0.f;
            #pragma unroll
            for (int mt = 0; mt < 4; ++mt) {
                ushort4 pk;
                unsigned short* pe = (unsigned short*)&pk;
                #pragma unroll
                for (int r = 0; r < 4; ++r) {
                    const float p = fast_exp2(accS[mt][r] - mrun);
                    const unsigned short pb = f2bf(p);
                    pe[r] = pb;
                    rs += bf2f(pb);
                }
                *(ushort4*)(pw + l15 * 64 + (((mt * 4 + quad) ^ pswz) << 2)) = pk;
            }
            rs += __shfl_xor(rs, 16);
            rs += __shfl_xor(rs, 32);
            lrun += rs;
            asm volatile("s_waitcnt lgkmcnt(0)" ::: "memory");
            __builtin_amdgcn_s_setprio(1);
            #pragma unroll
            for (int kk = 0; kk < 2; ++kk) {
                const bf16x8 pa = *(const bf16x8*)(pw + l15 * 64 + (((kk * 8 + quad * 2) ^ pswz) << 2));
                #pragma unroll
                for (int dt = 0; dt < 8; ++dt) {
                    const bf16x8 vf = *(const bf16x8*)(&ldsV[cur][(dt * 16 + l15) * 64 + (((kk * 4 + quad) ^ (l15 & 7)) << 3)]);
                    accO[dt] = __builtin_amdgcn_mfma_f32_16x16x32_bf16(pa, vf, accO[dt], 0, 0, 0);
                }
            }
            __builtin_amdgcn_s_setprio(0);
            __syncthreads();
            cur ^= 1;
        }
        float linv[4];
        #pragma unroll
        for (int r = 0; r < 4; ++r)
            linv[r] = __shfl(lrun, (lane & 48) | (quad << 2) | r);
        #pragma unroll
        for (int r = 0; r < 4; ++r) {
            const float inv = 1.0f / linv[r];
            unsigned short* orow = AV + ((size_t)bb * kS + qrow0 + quad * 4 + r) * kDM + h * kDH;
            #pragma unroll
            for (int dt = 0; dt < 8; ++dt)
                orow[dt * 16 + l15] = f2bf(accO[dt][r] * inv);
        }
    }
}

extern "C" void kernel_launch(void* const* d_in, const int* in_sizes, int n_in,
                              void* d_out, int out_size, void* d_ws, size_t ws_size,
                              hipStream_t stream) {
    const float* X   = (const float*)d_in[0];
    const float* lng = (const float*)d_in[1];
    const float* lnb = (const float*)d_in[2];
    const float* Wq  = (const float*)d_in[3];
    const float* bq  = (const float*)d_in[4];
    const float* Wk  = (const float*)d_in[5];
    const float* bk  = (const float*)d_in[6];
    const float* Wv  = (const float*)d_in[7];
    const float* bv  = (const float*)d_in[8];
    const float* Wo  = (const float*)d_in[9];
    const float* bo  = (const float*)d_in[10];
    float* out = (float*)d_out;

    char* p = (char*)d_ws;
    unsigned short* Xn  = (unsigned short*)p; p += (size_t)kM * kDM * 2;
    unsigned short* Wqt = (unsigned short*)p; p += (size_t)kDM * kDM * 2;  // Wq|Wk|Wv contiguous
    unsigned short* Wkt = (unsigned short*)p; p += (size_t)kDM * kDM * 2;
    unsigned short* Wvt = (unsigned short*)p; p += (size_t)kDM * kDM * 2;
    unsigned short* Wot = (unsigned short*)p; p += (size_t)kDM * kDM * 2;
    unsigned short* Qb  = (unsigned short*)p; p += (size_t)kM * kDM * 2;
    unsigned short* Kb  = (unsigned short*)p; p += (size_t)kM * kDM * 2;
    unsigned short* Vtb = (unsigned short*)p; p += (size_t)kM * kDM * 2;
    unsigned short* AV  = (unsigned short*)p; p += (size_t)kM * kDM * 2;
    // biasc lives in the AV region: consumed by gemm256's epilogue (QKV pass)
    // strictly before attn writes AV.
    float* biasc = (float*)AV;

    const float qscale = 0.08838834764831845f * 1.4426950408889634f;

    ln_kernel<<<dim3(kM), dim3(256), 0, stream>>>(X, lng, lnb, Xn);
    wt_kernel<<<dim3(32, 32, 4), dim3(256), 0, stream>>>(Wq, Wk, Wv, Wo, Wqt, Wkt, Wvt, Wot);
    bias_pack<<<dim3(24), dim3(256), 0, stream>>>(bq, bk, bv, biasc);
    // fused QKV GEMM: 256x128 tiles, grid 16x48 = 768 = 3 full CU rounds;
    // V written pre-transposed (vtr kernel eliminated)
    gemm256_kernel<<<dim3(16, 48), dim3(512), 0, stream>>>(Xn, Wqt, biasc, Qb, Kb, Vtb, qscale, 0);
    attn_kernel<<<dim3(32, 16), dim3(256), 0, stream>>>(Qb, Kb, Vtb, AV);
    // out-proj: same 256x128 kernel, fp32 out; grid 16x16 = 256 = 1 exact round
    gemm256_kernel<<<dim3(16, 16), dim3(512), 0, stream>>>(AV, Wot, bo, out, out, out, 1.0f, 1);
}

// Round 15
// 355.628 us; speedup vs baseline: 2.5568x; 1.0186x over previous
//
#include <hip/hip_runtime.h>
#include <cstdint>

constexpr int kDM = 2048;   // d_model
constexpr int kNH = 16;     // heads
constexpr int kDH = 128;    // head dim
constexpr int kS  = 2048;   // seq
constexpr int kM  = 4096;   // B*S rows

typedef __bf16 bf16x8 __attribute__((ext_vector_type(8)));
typedef float  f32x4  __attribute__((ext_vector_type(4)));

__device__ __forceinline__ unsigned short f2bf(float f) {
    union { float f; unsigned u; } v; v.f = f;
    unsigned u = v.u;
    u += 0x7fffu + ((u >> 16) & 1u);   // RNE
    return (unsigned short)(u >> 16);
}
__device__ __forceinline__ float bf2f(unsigned short b) {
    union { unsigned u; float f; } v; v.u = ((unsigned)b) << 16;
    return v.f;
}
__device__ __forceinline__ float fast_exp2(float x) {
#if __has_builtin(__builtin_amdgcn_exp2f)
    return __builtin_amdgcn_exp2f(x);
#else
    return exp2f(x);
#endif
}
// async global->LDS, 16B per lane, LDS dest = wave-uniform base + lane*16
__device__ __forceinline__ void load_lds16(const void* g, void* l) {
    auto gp = (__attribute__((address_space(1))) unsigned int*)(uintptr_t)g;
    auto lp = (__attribute__((address_space(3))) unsigned int*)(uintptr_t)l;
    __builtin_amdgcn_global_load_lds(gp, lp, 16, 0, 0);
}

// ------------- merged prep: ln (blocks 0..4095) | wt (4096..8191) | bias (8192..8215)
// R15: single launch replaces ln_kernel + wt_kernel + bias_pack. The three are
// independent (disjoint outputs, all 256-thread blocks); merging removes 2
// graph-node edges and co-schedules ln's light blocks with wt's transpose
// blocks (combined ~max, not sum). Bodies unchanged from the R14-validated
// versions.
__global__ __launch_bounds__(256) void prep_kernel(
        const float* __restrict__ X, const float* __restrict__ lng,
        const float* __restrict__ lnb, unsigned short* __restrict__ Xn,
        const float* __restrict__ Wq, const float* __restrict__ Wk,
        const float* __restrict__ Wv, const float* __restrict__ Wo,
        unsigned short* __restrict__ Tq, unsigned short* __restrict__ Tk,
        unsigned short* __restrict__ Tv, unsigned short* __restrict__ To,
        const float* __restrict__ bq, const float* __restrict__ bk,
        const float* __restrict__ bv, float* __restrict__ biasc) {
    const int bid = blockIdx.x;
    if (bid < kM) {
        // ---------------- LayerNorm: fp32 in -> bf16 out ----------------
        const int row = bid;
        const float* xr = X + (size_t)row * kDM;
        const float4 v0 = ((const float4*)xr)[threadIdx.x];
        const float4 v1 = ((const float4*)xr)[threadIdx.x + 256];
        float s  = v0.x + v0.y + v0.z + v0.w + v1.x + v1.y + v1.z + v1.w;
        float sq = v0.x*v0.x + v0.y*v0.y + v0.z*v0.z + v0.w*v0.w
                 + v1.x*v1.x + v1.y*v1.y + v1.z*v1.z + v1.w*v1.w;
        #pragma unroll
        for (int m = 1; m < 64; m <<= 1) { s += __shfl_xor(s, m); sq += __shfl_xor(sq, m); }
        __shared__ float ls[4], lq[4];
        if ((threadIdx.x & 63) == 0) { ls[threadIdx.x >> 6] = s; lq[threadIdx.x >> 6] = sq; }
        __syncthreads();
        s  = ls[0] + ls[1] + ls[2] + ls[3];
        sq = lq[0] + lq[1] + lq[2] + lq[3];
        const float mu   = s * (1.0f / kDM);
        const float rstd = rsqrtf(sq * (1.0f / kDM) - mu * mu + 1e-5f);
        unsigned short* xo = Xn + (size_t)row * kDM;
        {
            const float4 gg = ((const float4*)lng)[threadIdx.x];
            const float4 bb = ((const float4*)lnb)[threadIdx.x];
            ushort4 o;
            o.x = f2bf((v0.x - mu) * rstd * gg.x + bb.x);
            o.y = f2bf((v0.y - mu) * rstd * gg.y + bb.y);
            o.z = f2bf((v0.z - mu) * rstd * gg.z + bb.z);
            o.w = f2bf((v0.w - mu) * rstd * gg.w + bb.w);
            ((ushort4*)xo)[threadIdx.x] = o;
        }
        {
            const float4 gg = ((const float4*)lng)[threadIdx.x + 256];
            const float4 bb = ((const float4*)lnb)[threadIdx.x + 256];
            ushort4 o;
            o.x = f2bf((v1.x - mu) * rstd * gg.x + bb.x);
            o.y = f2bf((v1.y - mu) * rstd * gg.y + bb.y);
            o.z = f2bf((v1.z - mu) * rstd * gg.z + bb.z);
            o.w = f2bf((v1.w - mu) * rstd * gg.w + bb.w);
            ((ushort4*)xo)[threadIdx.x + 256] = o;
        }
    } else if (bid < kM + 4096) {
        // ---- weight transpose+cast: 64x64 tiles, odd-stride LDS, 16B stores ----
        const int idx = bid - kM;
        const int z = idx >> 10, rem = idx & 1023;
        const int by = rem >> 5, bx = rem & 31;
        const float* W; unsigned short* T;
        switch (z) {
            case 0:  W = Wq; T = Tq; break;
            case 1:  W = Wk; T = Tk; break;
            case 2:  W = Wv; T = Tv; break;
            default: W = Wo; T = To; break;
        }
        __shared__ float tile[64][65];
        const int t = threadIdx.x;
        const int r0 = by * 64, c0 = bx * 64;
        const int lr = t >> 4, lc = (t & 15) * 4;
        #pragma unroll
        for (int i = 0; i < 4; ++i) {
            const float4 v = *(const float4*)&W[(size_t)(r0 + lr + i * 16) * kDM + c0 + lc];
            float* tp = &tile[lr + i * 16][lc];
            tp[0] = v.x; tp[1] = v.y; tp[2] = v.z; tp[3] = v.w;
        }
        __syncthreads();
        const int g = t & 7;
        #pragma unroll
        for (int j = 0; j < 2; ++j) {
            const int orr = (t >> 3) + j * 32;
            union { unsigned short u[8]; uint4 v; } o;
            #pragma unroll
            for (int jj = 0; jj < 8; ++jj)
                o.u[jj] = f2bf(tile[g * 8 + jj][orr]);
            *(uint4*)&T[(size_t)(c0 + orr) * kDM + r0 + g * 8] = o.v;
        }
    } else {
        // ---- bias concat: [bq|bk|bv] -> 6144 floats ----
        const int i = (bid - kM - 4096) * 256 + threadIdx.x;
        biasc[i] = (i < 2048) ? bq[i] : ((i < 4096) ? bk[i - 2048] : bv[i - 4096]);
    }
}

// ------------- GEMM 256x128, 8-wave, BK=64, 2-phase counted-vmcnt pipeline -----
// R12 RACE FIX (validated R14: absmax 0.0078, replay-stable): ph1 reads ONLY A0
// rows (wr*64+mt*16 in [0,128)), ph2 reads ONLY A1 (128+wr*64+mt*16), so the
// boundary vmcnt(2)={B,A0} and mid-tile vmcnt(4) (drains A1^t) invariants hold
// exactly. Epilogue mrow = (mt&4)*32 + wr*64 + (mt&3)*16 matches.
// Epilogues: proj==2 writes V transposed [bh][dh][s] (vtr eliminated);
// fp32out path serves the out-proj (grid 16x16 = 1 exact CU round).
// Measured R14: QKV ~117us, VGPR 88, 0 bank conflicts.
__global__ __launch_bounds__(512, 2) void gemm256_kernel(
        const unsigned short* __restrict__ A, const unsigned short* __restrict__ Bt,
        const float* __restrict__ bias, void* __restrict__ C0, void* __restrict__ C1,
        void* __restrict__ C2, const float scale0, const int fp32out) {
    __shared__ __align__(16) unsigned short sA[2][2 * 128 * 64];   // 64KB
    __shared__ __align__(16) unsigned short sB[2][128 * 64];       // 32KB
    const int tid = threadIdx.x, lane = tid & 63, w = tid >> 6;
    const int quad = lane >> 4, l15 = lane & 15;
    const int wr = w >> 2, wc = w & 3;          // 2M x 4N wave grid
    const int m0 = blockIdx.x * 256, n0 = blockIdx.y * 128;
    const int srow = lane >> 3;
    const int scol = ((lane & 7) ^ srow) * 8;   // inverse-swizzled global source
    size_t aOff[2], bOff[2]; int lOff[2];
    #pragma unroll
    for (int i = 0; i < 2; ++i) {
        const int wrow = (i * 8 + w) * 8 + srow;     // row within a 128-row half
        aOff[i] = (size_t)(m0 + wrow) * kDM + scol;  // + h*128*kDM + kt*64
        bOff[i] = (size_t)(n0 + wrow) * kDM + scol;
        lOff[i] = (i * 8 + w) * 512;                 // + h*8192 (A only)
    }
    const int swz = l15 & 7;
    int colq[2];
    #pragma unroll
    for (int ks = 0; ks < 2; ++ks) colq[ks] = ((ks * 4 + quad) ^ swz) * 8;

#define STG_A(buf, h, kt) { \
    load_lds16(A  + aOff[0] + (size_t)(h) * (128 * kDM) + (kt) * 64, &sA[buf][(h) * 8192 + lOff[0]]); \
    load_lds16(A  + aOff[1] + (size_t)(h) * (128 * kDM) + (kt) * 64, &sA[buf][(h) * 8192 + lOff[1]]); }
#define STG_B(buf, kt) { \
    load_lds16(Bt + bOff[0] + (size_t)(kt) * 64, &sB[buf][lOff[0]]); \
    load_lds16(Bt + bOff[1] + (size_t)(kt) * 64, &sB[buf][lOff[1]]); }

    f32x4 acc[8][2] = {};
    // prologue: tile 0 (B, A0, A1); wait B+A0, keep A1 in flight
    STG_B(0, 0); STG_A(0, 0, 0); STG_A(0, 1, 0);
    asm volatile("s_waitcnt vmcnt(2)" ::: "memory");
    __builtin_amdgcn_s_barrier();

    const int NT = kDM / 64;                    // 32 K-tiles
    bf16x8 af[4][2], bfr[2][2];
    for (int t = 0; t < NT; ++t) {
        const int cur = t & 1, nxt = cur ^ 1;
        // ---- phase 1: read A0 rows (wr*64..wr*64+63) + B; stage B^{t+1}, A0^{t+1}
        #pragma unroll
        for (int mt = 0; mt < 4; ++mt)
            #pragma unroll
            for (int ks = 0; ks < 2; ++ks)
                af[mt][ks] = *(const bf16x8*)(&sA[cur][(wr * 64 + mt * 16 + l15) * 64 + colq[ks]]);
        #pragma unroll
        for (int nt = 0; nt < 2; ++nt)
            #pragma unroll
            for (int ks = 0; ks < 2; ++ks)
                bfr[nt][ks] = *(const bf16x8*)(&sB[cur][(wc * 32 + nt * 16 + l15) * 64 + colq[ks]]);
        if (t + 1 < NT) { STG_B(nxt, t + 1); STG_A(nxt, 0, t + 1); }
        __builtin_amdgcn_s_barrier();
        asm volatile("s_waitcnt lgkmcnt(0)" ::: "memory");
        __builtin_amdgcn_s_setprio(1);
        #pragma unroll
        for (int mt = 0; mt < 4; ++mt)
            #pragma unroll
            for (int nt = 0; nt < 2; ++nt)
                #pragma unroll
                for (int ks = 0; ks < 2; ++ks)
                    acc[mt][nt] = __builtin_amdgcn_mfma_f32_16x16x32_bf16(af[mt][ks], bfr[nt][ks], acc[mt][nt], 0, 0, 0);
        __builtin_amdgcn_s_setprio(0);
        if (t + 1 < NT) { asm volatile("s_waitcnt vmcnt(4)" ::: "memory"); }
        else            { asm volatile("s_waitcnt vmcnt(0)" ::: "memory"); }
        __builtin_amdgcn_s_barrier();           // A1^t certified resident (all waves)
        // ---- phase 2: read A1 rows (128+wr*64..); stage A1^{t+1}
        #pragma unroll
        for (int mt = 0; mt < 4; ++mt)
            #pragma unroll
            for (int ks = 0; ks < 2; ++ks)
                af[mt][ks] = *(const bf16x8*)(&sA[cur][(128 + wr * 64 + mt * 16 + l15) * 64 + colq[ks]]);
        if (t + 1 < NT) STG_A(nxt, 1, t + 1);
        __builtin_amdgcn_s_barrier();
        asm volatile("s_waitcnt lgkmcnt(0)" ::: "memory");
        __builtin_amdgcn_s_setprio(1);
        #pragma unroll
        for (int mt = 0; mt < 4; ++mt)
            #pragma unroll
            for (int nt = 0; nt < 2; ++nt)
                #pragma unroll
                for (int ks = 0; ks < 2; ++ks)
                    acc[4 + mt][nt] = __builtin_amdgcn_mfma_f32_16x16x32_bf16(af[mt][ks], bfr[nt][ks], acc[4 + mt][nt], 0, 0, 0);
        __builtin_amdgcn_s_setprio(0);
        if (t + 1 < NT) {
            asm volatile("s_waitcnt vmcnt(2)" ::: "memory");  // B+A0^{t+1} landed; A1^{t+1} flies
            __builtin_amdgcn_s_barrier();
        }
    }
#undef STG_A
#undef STG_B
    // ---- epilogue ----  (mrow matches the race-fixed read mapping)
    const int proj = n0 >> 11;
    if (fp32out) {
        float* Cb = (float*)C0;
        #pragma unroll
        for (int mt = 0; mt < 8; ++mt) {
            const int mrow = (mt & 4) * 32 + wr * 64 + (mt & 3) * 16;
            #pragma unroll
            for (int nt = 0; nt < 2; ++nt) {
                const int ng = n0 + wc * 32 + nt * 16 + l15;
                const float bv = bias[ng];
                #pragma unroll
                for (int r = 0; r < 4; ++r) {
                    const int mg = m0 + mrow + quad * 4 + r;
                    Cb[(size_t)mg * kDM + ng] = acc[mt][nt][r] + bv;
                }
            }
        }
    } else if (proj == 2) {
        // V: write transposed [bh][dh][s]; 4 consecutive s pack into ushort4
        unsigned short* Cb = (unsigned short*)C2;
        #pragma unroll
        for (int mt = 0; mt < 8; ++mt) {
            const int mrow = (mt & 4) * 32 + wr * 64 + (mt & 3) * 16;
            const int mgb = m0 + mrow + quad * 4;
            const int bb = mgb >> 11, ss = mgb & 2047;
            #pragma unroll
            for (int nt = 0; nt < 2; ++nt) {
                const int ng = n0 + wc * 32 + nt * 16 + l15;
                const float bv = bias[ng];
                const int col = ng & 2047;
                const int h = col >> 7, dh = col & 127;
                ushort4 o;
                o.x = f2bf(acc[mt][nt][0] + bv);
                o.y = f2bf(acc[mt][nt][1] + bv);
                o.z = f2bf(acc[mt][nt][2] + bv);
                o.w = f2bf(acc[mt][nt][3] + bv);
                *(ushort4*)&Cb[((size_t)(bb * kNH + h) * kDH + dh) * kS + ss] = o;
            }
        }
    } else {
        void* Cb = (proj == 0) ? C0 : C1;
        const float scl = (proj == 0) ? scale0 : 1.0f;
        #pragma unroll
        for (int mt = 0; mt < 8; ++mt) {
            const int mrow = (mt & 4) * 32 + wr * 64 + (mt & 3) * 16;
            #pragma unroll
            for (int nt = 0; nt < 2; ++nt) {
                const int ng = n0 + wc * 32 + nt * 16 + l15;
                const float bv = bias[ng];
                const int col = ng & 2047;
                const int h = col >> 7, dh = col & 127;
                #pragma unroll
                for (int r = 0; r < 4; ++r) {
                    const int mg = m0 + mrow + quad * 4 + r;
                    const float val = (acc[mt][nt][r] + bv) * scl;
                    const int bb = mg >> 11, ss = mg & 2047;
                    ((unsigned short*)Cb)[((size_t)(bb * kNH + h) * kS + ss) * kDH + dh] = f2bf(val);
                }
            }
        }
    }
}

// ------------- causal flash attention, S^T form, paired q-tiles -------------
// R4 structure (256 thr, dbuf K/V, T13 defer-max, T5 setprio). R7's dual-q-tile
// halved K/V traffic with ZERO time change -> K/V is L2/L3-resident; attn is
// not HBM-bound. Do not re-try traffic cuts.
__global__ __launch_bounds__(256, 2) void attn_kernel(
        const unsigned short* __restrict__ Q, const unsigned short* __restrict__ Kk,
        const unsigned short* __restrict__ Vt, unsigned short* __restrict__ AV) {
    __shared__ __align__(16) unsigned short ldsK[2][64 * 128];   // swizzled [key][d]
    __shared__ __align__(16) unsigned short ldsV[2][128 * 64];   // swizzled [d][key]
    __shared__ __align__(16) unsigned short ldsP[4 * 16 * 64];   // per-wave swizzled [q][key]
    const int bh = blockIdx.x, pr = blockIdx.y;
    const unsigned short* Qb = Q  + (size_t)bh * kS * kDH;
    const unsigned short* Kb = Kk + (size_t)bh * kS * kDH;
    const unsigned short* Vb = Vt + (size_t)bh * kDH * kS;
    const int tid = threadIdx.x, lane = tid & 63, w = tid >> 6;
    const int quad = lane >> 4, l15 = lane & 15;
    int kSrc[4], vSrc[4], ldst[4];
    #pragma unroll
    for (int i = 0; i < 4; ++i) {
        const int c = w * 4 + i;
        const int rK = c * 4 + (lane >> 4);
        const int gK = (lane & 15) ^ (rK & 15);
        kSrc[i] = rK * kDH + gK * 8;
        const int dV = c * 8 + (lane >> 3);
        const int gV = (lane & 7) ^ (dV & 7);
        vSrc[i] = dV * kS + gV * 8;
        ldst[i] = c * 512;
    }
    unsigned short* pw = ldsP + w * 1024;
    const int pswz = 2 * (l15 & 7);
    const int bb = bh >> 4, h = bh & 15;
    for (int half = 0; half < 2; ++half) {
        const int qt = half ? (31 - pr) : pr;
        const int qrow0 = qt * 64 + w * 16;
        bf16x8 qf[4];
        #pragma unroll
        for (int kk = 0; kk < 4; ++kk)
            qf[kk] = *(const bf16x8*)(Qb + (size_t)(qrow0 + l15) * kDH + kk * 32 + quad * 8);
        f32x4 accO[8] = {};
        float mrun = -3.0e38f, lrun = 0.0f;
        #pragma unroll
        for (int i = 0; i < 4; ++i) {
            load_lds16(Kb + kSrc[i], &ldsK[0][ldst[i]]);
            load_lds16(Vb + vSrc[i], &ldsV[0][ldst[i]]);
        }
        __syncthreads();
        int cur = 0;
        for (int kt = 0; kt <= qt; ++kt) {
            if (kt < qt) {
                #pragma unroll
                for (int i = 0; i < 4; ++i) {
                    load_lds16(Kb + (size_t)(kt + 1) * (64 * kDH) + kSrc[i], &ldsK[cur ^ 1][ldst[i]]);
                    load_lds16(Vb + (kt + 1) * 64 + vSrc[i], &ldsV[cur ^ 1][ldst[i]]);
                }
            }
            f32x4 accS[4] = {};
            __builtin_amdgcn_s_setprio(1);
            #pragma unroll
            for (int kk = 0; kk < 4; ++kk) {
                bf16x8 kf[4];
                #pragma unroll
                for (int mt = 0; mt < 4; ++mt)
                    kf[mt] = *(const bf16x8*)(&ldsK[cur][(mt * 16 + l15) * 128 + (((kk * 4 + quad) ^ l15) << 3)]);
                #pragma unroll
                for (int mt = 0; mt < 4; ++mt)
                    accS[mt] = __builtin_amdgcn_mfma_f32_16x16x32_bf16(kf[mt], qf[kk], accS[mt], 0, 0, 0);
            }
            __builtin_amdgcn_s_setprio(0);
            if (kt == qt) {
                const int ql = w * 16 + l15;
                #pragma unroll
                for (int mt = 0; mt < 4; ++mt)
                    #pragma unroll
                    for (int r = 0; r < 4; ++r)
                        if (mt * 16 + quad * 4 + r > ql) accS[mt][r] = -3.0e38f;
            }
            float mx = accS[0][0];
            #pragma unroll
            for (int mt = 0; mt < 4; ++mt)
                #pragma unroll
                for (int r = 0; r < 4; ++r) mx = fmaxf(mx, accS[mt][r]);
            mx = fmaxf(mx, __shfl_xor(mx, 16));
            mx = fmaxf(mx, __shfl_xor(mx, 32));
            if (!__all(mx - mrun <= 8.0f)) {    // T13 defer-max
                const float mnew = fmaxf(mrun, mx);
                const float al = fast_exp2(mrun - mnew);
                lrun *= al;
                float albr[4];
                #pragma unroll
                for (int r = 0; r < 4; ++r)
                    albr[r] = __shfl(al, (lane & 48) | (quad << 2) | r);
                #pragma unroll
                for (int dt = 0; dt < 8; ++dt)
                    #pragma unroll
                    for (int r = 0; r < 4; ++r)
                        accO[dt][r] *= albr[r];
                mrun = mnew;
            }
            float rs = 0.f;
            #pragma unroll
            for (int mt = 0; mt < 4; ++mt) {
                ushort4 pk;
                unsigned short* pe = (unsigned short*)&pk;
                #pragma unroll
                for (int r = 0; r < 4; ++r) {
                    const float p = fast_exp2(accS[mt][r] - mrun);
                    const unsigned short pb = f2bf(p);
                    pe[r] = pb;
                    rs += bf2f(pb);
                }
                *(ushort4*)(pw + l15 * 64 + (((mt * 4 + quad) ^ pswz) << 2)) = pk;
            }
            rs += __shfl_xor(rs, 16);
            rs += __shfl_xor(rs, 32);
            lrun += rs;
            asm volatile("s_waitcnt lgkmcnt(0)" ::: "memory");
            __builtin_amdgcn_s_setprio(1);
            #pragma unroll
            for (int kk = 0; kk < 2; ++kk) {
                const bf16x8 pa = *(const bf16x8*)(pw + l15 * 64 + (((kk * 8 + quad * 2) ^ pswz) << 2));
                #pragma unroll
                for (int dt = 0; dt < 8; ++dt) {
                    const bf16x8 vf = *(const bf16x8*)(&ldsV[cur][(dt * 16 + l15) * 64 + (((kk * 4 + quad) ^ (l15 & 7)) << 3)]);
                    accO[dt] = __builtin_amdgcn_mfma_f32_16x16x32_bf16(pa, vf, accO[dt], 0, 0, 0);
                }
            }
            __builtin_amdgcn_s_setprio(0);
            __syncthreads();
            cur ^= 1;
        }
        float linv[4];
        #pragma unroll
        for (int r = 0; r < 4; ++r)
            linv[r] = __shfl(lrun, (lane & 48) | (quad << 2) | r);
        #pragma unroll
        for (int r = 0; r < 4; ++r) {
            const float inv = 1.0f / linv[r];
            unsigned short* orow = AV + ((size_t)bb * kS + qrow0 + quad * 4 + r) * kDM + h * kDH;
            #pragma unroll
            for (int dt = 0; dt < 8; ++dt)
                orow[dt * 16 + l15] = f2bf(accO[dt][r] * inv);
        }
    }
}

extern "C" void kernel_launch(void* const* d_in, const int* in_sizes, int n_in,
                              void* d_out, int out_size, void* d_ws, size_t ws_size,
                              hipStream_t stream) {
    const float* X   = (const float*)d_in[0];
    const float* lng = (const float*)d_in[1];
    const float* lnb = (const float*)d_in[2];
    const float* Wq  = (const float*)d_in[3];
    const float* bq  = (const float*)d_in[4];
    const float* Wk  = (const float*)d_in[5];
    const float* bk  = (const float*)d_in[6];
    const float* Wv  = (const float*)d_in[7];
    const float* bv  = (const float*)d_in[8];
    const float* Wo  = (const float*)d_in[9];
    const float* bo  = (const float*)d_in[10];
    float* out = (float*)d_out;

    char* p = (char*)d_ws;
    unsigned short* Xn  = (unsigned short*)p; p += (size_t)kM * kDM * 2;
    unsigned short* Wqt = (unsigned short*)p; p += (size_t)kDM * kDM * 2;  // Wq|Wk|Wv contiguous
    unsigned short* Wkt = (unsigned short*)p; p += (size_t)kDM * kDM * 2;
    unsigned short* Wvt = (unsigned short*)p; p += (size_t)kDM * kDM * 2;
    unsigned short* Wot = (unsigned short*)p; p += (size_t)kDM * kDM * 2;
    unsigned short* Qb  = (unsigned short*)p; p += (size_t)kM * kDM * 2;
    unsigned short* Kb  = (unsigned short*)p; p += (size_t)kM * kDM * 2;
    unsigned short* Vtb = (unsigned short*)p; p += (size_t)kM * kDM * 2;
    unsigned short* AV  = (unsigned short*)p; p += (size_t)kM * kDM * 2;
    // biasc lives in the AV region: consumed by gemm256's epilogue (QKV pass)
    // strictly before attn writes AV.
    float* biasc = (float*)AV;

    const float qscale = 0.08838834764831845f * 1.4426950408889634f;

    // merged prep: ln (4096) | wt (4096) | bias (24) in one launch
    prep_kernel<<<dim3(kM + 4096 + 24), dim3(256), 0, stream>>>(
        X, lng, lnb, Xn, Wq, Wk, Wv, Wo, Wqt, Wkt, Wvt, Wot, bq, bk, bv, biasc);
    // fused QKV GEMM: 256x128 tiles, grid 16x48 = 768 = 3 full CU rounds;
    // V written pre-transposed (vtr kernel eliminated)
    gemm256_kernel<<<dim3(16, 48), dim3(512), 0, stream>>>(Xn, Wqt, biasc, Qb, Kb, Vtb, qscale, 0);
    attn_kernel<<<dim3(32, 16), dim3(256), 0, stream>>>(Qb, Kb, Vtb, AV);
    // out-proj: same 256x128 kernel, fp32 out; grid 16x16 = 256 = 1 exact round
    gemm256_kernel<<<dim3(16, 16), dim3(512), 0, stream>>>(AV, Wot, bo, out, out, out, 1.0f, 1);
}